// Round 1
// baseline (705.761 us; speedup 1.0000x reference)
//
#include <hip/hip_runtime.h>
#include <hip/hip_bf16.h>

#define NN 20000
#define EF 640000
#define EG 160000

// ---------------------------------------------------------------------------
// QKV: [20000,128] @ 128x128 (x3) -> Q,K,V  (grid.y selects Wq/Wk/Wv halves)
// BM=64, BN=64, BK=64, 256 threads, 4x4 acc per thread.
// ---------------------------------------------------------------------------
__global__ __launch_bounds__(256) void qkv_gemm(
    const float* __restrict__ h,
    const float* __restrict__ Wq, const float* __restrict__ bq,
    const float* __restrict__ Wk, const float* __restrict__ bk,
    const float* __restrict__ Wv, const float* __restrict__ bv,
    float* __restrict__ Qo, float* __restrict__ Ko, float* __restrict__ Vo)
{
    __shared__ float Al[64][68];
    __shared__ float Bl[64][68];
    const int bm = blockIdx.x;
    const int bsel = blockIdx.y;           // 0..5
    const float* W; const float* bias; float* Out;
    if (bsel < 2)      { W = Wq; bias = bq; Out = Qo; }
    else if (bsel < 4) { W = Wk; bias = bk; Out = Ko; }
    else               { W = Wv; bias = bv; Out = Vo; }
    const int col0 = (bsel & 1) * 64;
    const int tid = threadIdx.x;
    const int row0 = bm * 64;
    const int ty = tid >> 4, tx = tid & 15;

    float acc[4][4];
    #pragma unroll
    for (int i = 0; i < 4; ++i)
        #pragma unroll
        for (int j = 0; j < 4; ++j) acc[i][j] = 0.f;

    for (int kt = 0; kt < 2; ++kt) {
        if (kt) __syncthreads();
        // load A slice: 64 rows x 64 k  (1024 float4, 4 per thread)
        #pragma unroll
        for (int i = 0; i < 4; ++i) {
            int f4 = tid + i * 256;
            int r = f4 >> 4, c = (f4 & 15) << 2;
            float4 v = make_float4(0.f, 0.f, 0.f, 0.f);
            int gr = row0 + r;
            if (gr < NN) v = *(const float4*)(h + (size_t)gr * 128 + kt * 64 + c);
            *(float4*)(&Al[r][c]) = v;
        }
        // load B slice: 64 k x 64 n
        #pragma unroll
        for (int i = 0; i < 4; ++i) {
            int f4 = tid + i * 256;
            int r = f4 >> 4, c = (f4 & 15) << 2;
            float4 v = *(const float4*)(W + (size_t)(kt * 64 + r) * 128 + col0 + c);
            *(float4*)(&Bl[r][c]) = v;
        }
        __syncthreads();
        #pragma unroll
        for (int k = 0; k < 64; ++k) {
            float a[4];
            #pragma unroll
            for (int i = 0; i < 4; ++i) a[i] = Al[ty * 4 + i][k];
            float4 b4 = *(const float4*)(&Bl[k][tx * 4]);
            float b[4] = {b4.x, b4.y, b4.z, b4.w};
            #pragma unroll
            for (int i = 0; i < 4; ++i)
                #pragma unroll
                for (int j = 0; j < 4; ++j) acc[i][j] += a[i] * b[j];
        }
    }
    #pragma unroll
    for (int i = 0; i < 4; ++i) {
        int gr = row0 + ty * 4 + i;
        if (gr < NN) {
            #pragma unroll
            for (int j = 0; j < 4; ++j) {
                int c = col0 + tx * 4 + j;
                Out[(size_t)gr * 128 + c] = acc[i][j] + bias[c];
            }
        }
    }
}

// ---------------------------------------------------------------------------
// score1 for all full-graph edges: 8 lanes per edge (one per head)
// ---------------------------------------------------------------------------
__global__ __launch_bounds__(256) void score_kernel(
    const float* __restrict__ Q, const float* __restrict__ K,
    const int* __restrict__ src, const int* __restrict__ dst,
    const float* __restrict__ adj2, const float* __restrict__ rel,
    float* __restrict__ score)
{
    int tid = blockIdx.x * 256 + threadIdx.x;   // over EF*8 = 5,120,000
    if (tid >= EF * 8) return;
    int e = tid >> 3, hh = tid & 7;
    int s = src[e], d = dst[e];
    const float4* Kp = (const float4*)(K + (size_t)s * 128 + hh * 16);
    const float4* Qp = (const float4*)(Q + (size_t)d * 128 + hh * 16);
    float dot = 0.f;
    #pragma unroll
    for (int j = 0; j < 4; ++j) {
        float4 a = Kp[j]; float4 b = Qp[j];
        dot += a.x * b.x + a.y * b.y + a.z * b.z + a.w * b.w;
    }
    dot *= 0.25f;  // / sqrt(16)
    float sc = __expf(fminf(fmaxf(dot, -5.f), 5.f) * adj2[e]) + rel[e];
    score[tid] = sc;
}

// ---------------------------------------------------------------------------
// g-edge pipeline (one wave per g-edge):
//   gs = score1[emap[i]] (pre-update)
//   pe = e_row @ Wpe + bpe  (butterfly reduce)
//   score[emap[i]] = clip(gs) + pe
//   tmp_row (into e_out region) = gs @ Wap + bap + e_row
// ---------------------------------------------------------------------------
__global__ __launch_bounds__(256) void gedge_a(
    const float* __restrict__ efeat, const int* __restrict__ emap,
    const float* __restrict__ Wpe, const float* __restrict__ bpe,
    const float* __restrict__ Wap, const float* __restrict__ bap,
    float* __restrict__ score, float* __restrict__ tmp)
{
    int lane = threadIdx.x & 63;
    int wid = (blockIdx.x << 2) | (threadIdx.x >> 6);
    int nw = gridDim.x << 2;
    for (int i = wid; i < EG; i += nw) {
        int fidx = __builtin_amdgcn_readfirstlane(emap[i]);
        float gs[8];
        #pragma unroll
        for (int hh = 0; hh < 8; ++hh) gs[hh] = score[fidx * 8 + hh];
        float e0 = efeat[(size_t)i * 128 + lane];
        float e1 = efeat[(size_t)i * 128 + 64 + lane];
        // partial proj_e
        float p[8];
        #pragma unroll
        for (int hh = 0; hh < 8; ++hh)
            p[hh] = e0 * Wpe[lane * 8 + hh] + e1 * Wpe[(64 + lane) * 8 + hh];
        #pragma unroll
        for (int s = 32; s >= 1; s >>= 1) {
            #pragma unroll
            for (int hh = 0; hh < 8; ++hh)
                p[hh] += __shfl_xor(p[hh], s);
        }
        // lanes 0..7 update score row
        float pv = p[0], gv = gs[0];
        #pragma unroll
        for (int hh = 1; hh < 8; ++hh) {
            bool m = (lane == hh);
            pv = m ? p[hh] : pv;
            gv = m ? gs[hh] : gv;
        }
        if (lane < 8)
            score[fidx * 8 + lane] = fminf(fmaxf(gv, -5.f), 5.f) + bpe[lane] + pv;
        // attention projection + residual e
        float ap0 = bap[lane], ap1 = bap[64 + lane];
        #pragma unroll
        for (int hh = 0; hh < 8; ++hh) {
            ap0 += gs[hh] * Wap[hh * 128 + lane];
            ap1 += gs[hh] * Wap[hh * 128 + 64 + lane];
        }
        tmp[(size_t)i * 128 + lane] = ap0 + e0;
        tmp[(size_t)i * 128 + 64 + lane] = ap1 + e1;
    }
}

// ---------------------------------------------------------------------------
// e_out = tmp @ Woute + boute, in place on d_out e-section.
// BM=32 rows, full N=128 per block (in-place safe), BK=64.
// ---------------------------------------------------------------------------
__global__ __launch_bounds__(256) void eout_gemm(
    float* __restrict__ io, const float* __restrict__ Woute,
    const float* __restrict__ boute)
{
    __shared__ float Al[32][132];
    __shared__ float Bl[64][132];
    const int row0 = blockIdx.x * 32;
    const int tid = threadIdx.x;
    const int ty = tid >> 5, tx = tid & 31;   // 8 x 32

    // load A: 32 rows x 128 (1024 float4)
    #pragma unroll
    for (int i = 0; i < 4; ++i) {
        int f4 = tid + i * 256;
        int r = f4 >> 5, c = (f4 & 31) << 2;
        *(float4*)(&Al[r][c]) = *(const float4*)(io + (size_t)(row0 + r) * 128 + c);
    }
    float acc[4][4];
    #pragma unroll
    for (int i = 0; i < 4; ++i)
        #pragma unroll
        for (int j = 0; j < 4; ++j) acc[i][j] = 0.f;

    for (int kt = 0; kt < 2; ++kt) {
        if (kt) __syncthreads();
        #pragma unroll
        for (int i = 0; i < 8; ++i) {
            int f4 = tid + i * 256;
            int r = f4 >> 5, c = (f4 & 31) << 2;
            *(float4*)(&Bl[r][c]) = *(const float4*)(Woute + (size_t)(kt * 64 + r) * 128 + c);
        }
        __syncthreads();
        #pragma unroll
        for (int k = 0; k < 64; ++k) {
            float a[4];
            #pragma unroll
            for (int i = 0; i < 4; ++i) a[i] = Al[ty * 4 + i][kt * 64 + k];
            float4 b4 = *(const float4*)(&Bl[k][tx * 4]);
            float b[4] = {b4.x, b4.y, b4.z, b4.w};
            #pragma unroll
            for (int i = 0; i < 4; ++i)
                #pragma unroll
                for (int j = 0; j < 4; ++j) acc[i][j] += a[i] * b[j];
        }
    }
    #pragma unroll
    for (int i = 0; i < 4; ++i)
        #pragma unroll
        for (int j = 0; j < 4; ++j)
            io[(size_t)(row0 + ty * 4 + i) * 128 + tx * 4 + j] =
                acc[i][j] + boute[tx * 4 + j];
}

// ---------------------------------------------------------------------------
// aggregation: thread per (edge, d) -> atomicAdd into wV; lanes d<8 also z.
// ---------------------------------------------------------------------------
__global__ __launch_bounds__(256) void aggregate(
    const float* __restrict__ V, const int* __restrict__ src,
    const int* __restrict__ dst, const float* __restrict__ score,
    float* __restrict__ wV, float* __restrict__ z)
{
    int tid = blockIdx.x * 256 + threadIdx.x;   // over EF*128 = 81,920,000
    int e = tid >> 7;
    if (e >= EF) return;
    int d = tid & 127;
    int s = src[e], dd = dst[e];
    float sc = score[e * 8 + (d >> 4)];
    float s2 = __expf(fminf(fmaxf(sc, -5.f), 5.f));
    float val = V[(size_t)s * 128 + d] * s2;
    atomicAdd(&wV[(size_t)dd * 128 + d], val);
    if (d < 8) {
        float sh = score[e * 8 + d];
        atomicAdd(&z[dd * 8 + d], __expf(fminf(fmaxf(sh, -5.f), 5.f)));
    }
}

// ---------------------------------------------------------------------------
// h_out = (wV / (z + 1e-6)) @ Wout + bout.  Wave per node, Wout in LDS.
// ---------------------------------------------------------------------------
__global__ __launch_bounds__(256) void hout_kernel(
    const float* __restrict__ wV, const float* __restrict__ z,
    const float* __restrict__ Wout, const float* __restrict__ bout,
    float* __restrict__ out)
{
    __shared__ float Wl[128 * 128];
    for (int i = threadIdx.x; i < 4096; i += 256)
        ((float4*)Wl)[i] = ((const float4*)Wout)[i];
    __syncthreads();
    int lane = threadIdx.x & 63;
    int wid = (blockIdx.x << 2) | (threadIdx.x >> 6);
    int nw = gridDim.x << 2;
    for (int n = wid; n < NN; n += nw) {
        float z0 = z[n * 8 + (lane >> 4)] + 1e-6f;
        float z1 = z[n * 8 + 4 + (lane >> 4)] + 1e-6f;
        float w0 = wV[(size_t)n * 128 + lane] / z0;
        float w1 = wV[(size_t)n * 128 + 64 + lane] / z1;
        float acc0 = 0.f, acc1 = 0.f, acc0b = 0.f, acc1b = 0.f;
        #pragma unroll
        for (int k = 0; k < 64; ++k) {
            float b0 = __shfl(w0, k);
            acc0  += b0 * Wl[k * 128 + lane];
            acc1  += b0 * Wl[k * 128 + 64 + lane];
            float b1 = __shfl(w1, k);
            acc0b += b1 * Wl[(64 + k) * 128 + lane];
            acc1b += b1 * Wl[(64 + k) * 128 + 64 + lane];
        }
        out[(size_t)n * 128 + lane] = acc0 + acc0b + bout[lane];
        out[(size_t)n * 128 + 64 + lane] = acc1 + acc1b + bout[64 + lane];
    }
}

extern "C" void kernel_launch(void* const* d_in, const int* in_sizes, int n_in,
                              void* d_out, int out_size, void* d_ws, size_t ws_size,
                              hipStream_t stream)
{
    const float* h    = (const float*)d_in[0];
    const float* e    = (const float*)d_in[1];
    const float* adj2 = (const float*)d_in[2];
    const float* rel  = (const float*)d_in[3];
    const int*   src  = (const int*)d_in[4];
    const int*   dst  = (const int*)d_in[5];
    const int*   emap = (const int*)d_in[6];
    const float* Wq = (const float*)d_in[7];   const float* bq = (const float*)d_in[8];
    const float* Wk = (const float*)d_in[9];   const float* bk = (const float*)d_in[10];
    const float* Wv = (const float*)d_in[11];  const float* bv = (const float*)d_in[12];
    const float* Wpe = (const float*)d_in[13]; const float* bpe = (const float*)d_in[14];
    const float* Wap = (const float*)d_in[15]; const float* bap = (const float*)d_in[16];
    const float* Wout = (const float*)d_in[17]; const float* bout = (const float*)d_in[18];
    const float* Woute = (const float*)d_in[19]; const float* boute = (const float*)d_in[20];

    float* ws    = (float*)d_ws;
    float* Q     = ws;                 // 2,560,000
    float* K     = ws + 2560000;       // 2,560,000
    float* V     = ws + 5120000;       // 2,560,000
    float* score = ws + 7680000;       // 5,120,000
    float* wV    = ws + 12800000;      // 2,560,000
    float* z     = ws + 15360000;      //   160,000
    float* h_out = (float*)d_out;
    float* e_out = (float*)d_out + 2560000;

    hipMemsetAsync(wV, 0, (2560000 + 160000) * sizeof(float), stream);

    qkv_gemm<<<dim3(313, 6), 256, 0, stream>>>(h, Wq, bq, Wk, bk, Wv, bv, Q, K, V);
    score_kernel<<<20000, 256, 0, stream>>>(Q, K, src, dst, adj2, rel, score);
    gedge_a<<<1250, 256, 0, stream>>>(e, emap, Wpe, bpe, Wap, bap, score, e_out);
    eout_gemm<<<5000, 256, 0, stream>>>(e_out, Woute, boute);
    aggregate<<<320000, 256, 0, stream>>>(V, src, dst, score, wV, z);
    hout_kernel<<<512, 256, 0, stream>>>(wV, z, Wout, bout, h_out);
}

// Round 2
// 595.495 us; speedup vs baseline: 1.1852x; 1.1852x over previous
//
#include <hip/hip_runtime.h>
#include <hip/hip_bf16.h>

#define NN 20000
#define EF 640000
#define EG 160000

// ---------------------------------------------------------------------------
// QKV: [20000,128] @ 128x128 (x3) -> Q,K,V  (grid.y selects Wq/Wk/Wv halves)
// ---------------------------------------------------------------------------
__global__ __launch_bounds__(256) void qkv_gemm(
    const float* __restrict__ h,
    const float* __restrict__ Wq, const float* __restrict__ bq,
    const float* __restrict__ Wk, const float* __restrict__ bk,
    const float* __restrict__ Wv, const float* __restrict__ bv,
    float* __restrict__ Qo, float* __restrict__ Ko, float* __restrict__ Vo)
{
    __shared__ float Al[64][68];
    __shared__ float Bl[64][68];
    const int bm = blockIdx.x;
    const int bsel = blockIdx.y;           // 0..5
    const float* W; const float* bias; float* Out;
    if (bsel < 2)      { W = Wq; bias = bq; Out = Qo; }
    else if (bsel < 4) { W = Wk; bias = bk; Out = Ko; }
    else               { W = Wv; bias = bv; Out = Vo; }
    const int col0 = (bsel & 1) * 64;
    const int tid = threadIdx.x;
    const int row0 = bm * 64;
    const int ty = tid >> 4, tx = tid & 15;

    float acc[4][4];
    #pragma unroll
    for (int i = 0; i < 4; ++i)
        #pragma unroll
        for (int j = 0; j < 4; ++j) acc[i][j] = 0.f;

    for (int kt = 0; kt < 2; ++kt) {
        if (kt) __syncthreads();
        #pragma unroll
        for (int i = 0; i < 4; ++i) {
            int f4 = tid + i * 256;
            int r = f4 >> 4, c = (f4 & 15) << 2;
            float4 v = make_float4(0.f, 0.f, 0.f, 0.f);
            int gr = row0 + r;
            if (gr < NN) v = *(const float4*)(h + (size_t)gr * 128 + kt * 64 + c);
            *(float4*)(&Al[r][c]) = v;
        }
        #pragma unroll
        for (int i = 0; i < 4; ++i) {
            int f4 = tid + i * 256;
            int r = f4 >> 4, c = (f4 & 15) << 2;
            float4 v = *(const float4*)(W + (size_t)(kt * 64 + r) * 128 + col0 + c);
            *(float4*)(&Bl[r][c]) = v;
        }
        __syncthreads();
        #pragma unroll
        for (int k = 0; k < 64; ++k) {
            float a[4];
            #pragma unroll
            for (int i = 0; i < 4; ++i) a[i] = Al[ty * 4 + i][k];
            float4 b4 = *(const float4*)(&Bl[k][tx * 4]);
            float b[4] = {b4.x, b4.y, b4.z, b4.w};
            #pragma unroll
            for (int i = 0; i < 4; ++i)
                #pragma unroll
                for (int j = 0; j < 4; ++j) acc[i][j] += a[i] * b[j];
        }
    }
    #pragma unroll
    for (int i = 0; i < 4; ++i) {
        int gr = row0 + ty * 4 + i;
        if (gr < NN) {
            #pragma unroll
            for (int j = 0; j < 4; ++j) {
                int c = col0 + tx * 4 + j;
                Out[(size_t)gr * 128 + c] = acc[i][j] + bias[c];
            }
        }
    }
}

// ---------------------------------------------------------------------------
// score1 for all full-graph edges: 8 lanes per edge (one per head)
// ---------------------------------------------------------------------------
__global__ __launch_bounds__(256) void score_kernel(
    const float* __restrict__ Q, const float* __restrict__ K,
    const int* __restrict__ src, const int* __restrict__ dst,
    const float* __restrict__ adj2, const float* __restrict__ rel,
    float* __restrict__ score)
{
    int tid = blockIdx.x * 256 + threadIdx.x;   // over EF*8 = 5,120,000
    if (tid >= EF * 8) return;
    int e = tid >> 3, hh = tid & 7;
    int s = src[e], d = dst[e];
    const float4* Kp = (const float4*)(K + (size_t)s * 128 + hh * 16);
    const float4* Qp = (const float4*)(Q + (size_t)d * 128 + hh * 16);
    float dot = 0.f;
    #pragma unroll
    for (int j = 0; j < 4; ++j) {
        float4 a = Kp[j]; float4 b = Qp[j];
        dot += a.x * b.x + a.y * b.y + a.z * b.z + a.w * b.w;
    }
    dot *= 0.25f;  // / sqrt(16)
    float sc = __expf(fminf(fmaxf(dot, -5.f), 5.f) * adj2[e]) + rel[e];
    score[tid] = sc;
}

// ---------------------------------------------------------------------------
// g-edge pipeline (one wave per g-edge)
// ---------------------------------------------------------------------------
__global__ __launch_bounds__(256) void gedge_a(
    const float* __restrict__ efeat, const int* __restrict__ emap,
    const float* __restrict__ Wpe, const float* __restrict__ bpe,
    const float* __restrict__ Wap, const float* __restrict__ bap,
    float* __restrict__ score, float* __restrict__ tmp)
{
    int lane = threadIdx.x & 63;
    int wid = (blockIdx.x << 2) | (threadIdx.x >> 6);
    int nw = gridDim.x << 2;
    for (int i = wid; i < EG; i += nw) {
        int fidx = __builtin_amdgcn_readfirstlane(emap[i]);
        float gs[8];
        #pragma unroll
        for (int hh = 0; hh < 8; ++hh) gs[hh] = score[fidx * 8 + hh];
        float e0 = efeat[(size_t)i * 128 + lane];
        float e1 = efeat[(size_t)i * 128 + 64 + lane];
        float p[8];
        #pragma unroll
        for (int hh = 0; hh < 8; ++hh)
            p[hh] = e0 * Wpe[lane * 8 + hh] + e1 * Wpe[(64 + lane) * 8 + hh];
        #pragma unroll
        for (int s = 32; s >= 1; s >>= 1) {
            #pragma unroll
            for (int hh = 0; hh < 8; ++hh)
                p[hh] += __shfl_xor(p[hh], s);
        }
        float pv = p[0], gv = gs[0];
        #pragma unroll
        for (int hh = 1; hh < 8; ++hh) {
            bool m = (lane == hh);
            pv = m ? p[hh] : pv;
            gv = m ? gs[hh] : gv;
        }
        if (lane < 8)
            score[fidx * 8 + lane] = fminf(fmaxf(gv, -5.f), 5.f) + bpe[lane] + pv;
        float ap0 = bap[lane], ap1 = bap[64 + lane];
        #pragma unroll
        for (int hh = 0; hh < 8; ++hh) {
            ap0 += gs[hh] * Wap[hh * 128 + lane];
            ap1 += gs[hh] * Wap[hh * 128 + 64 + lane];
        }
        tmp[(size_t)i * 128 + lane] = ap0 + e0;
        tmp[(size_t)i * 128 + 64 + lane] = ap1 + e1;
    }
}

// ---------------------------------------------------------------------------
// e_out = tmp @ Woute + boute, in place on d_out e-section.
// ---------------------------------------------------------------------------
__global__ __launch_bounds__(256) void eout_gemm(
    float* __restrict__ io, const float* __restrict__ Woute,
    const float* __restrict__ boute)
{
    __shared__ float Al[32][132];
    __shared__ float Bl[64][132];
    const int row0 = blockIdx.x * 32;
    const int tid = threadIdx.x;
    const int ty = tid >> 5, tx = tid & 31;   // 8 x 32

    #pragma unroll
    for (int i = 0; i < 4; ++i) {
        int f4 = tid + i * 256;
        int r = f4 >> 5, c = (f4 & 31) << 2;
        *(float4*)(&Al[r][c]) = *(const float4*)(io + (size_t)(row0 + r) * 128 + c);
    }
    float acc[4][4];
    #pragma unroll
    for (int i = 0; i < 4; ++i)
        #pragma unroll
        for (int j = 0; j < 4; ++j) acc[i][j] = 0.f;

    for (int kt = 0; kt < 2; ++kt) {
        if (kt) __syncthreads();
        #pragma unroll
        for (int i = 0; i < 8; ++i) {
            int f4 = tid + i * 256;
            int r = f4 >> 5, c = (f4 & 31) << 2;
            *(float4*)(&Bl[r][c]) = *(const float4*)(Woute + (size_t)(kt * 64 + r) * 128 + c);
        }
        __syncthreads();
        #pragma unroll
        for (int k = 0; k < 64; ++k) {
            float a[4];
            #pragma unroll
            for (int i = 0; i < 4; ++i) a[i] = Al[ty * 4 + i][kt * 64 + k];
            float4 b4 = *(const float4*)(&Bl[k][tx * 4]);
            float b[4] = {b4.x, b4.y, b4.z, b4.w};
            #pragma unroll
            for (int i = 0; i < 4; ++i)
                #pragma unroll
                for (int j = 0; j < 4; ++j) acc[i][j] += a[i] * b[j];
        }
    }
    #pragma unroll
    for (int i = 0; i < 4; ++i)
        #pragma unroll
        for (int j = 0; j < 4; ++j)
            io[(size_t)(row0 + ty * 4 + i) * 128 + tx * 4 + j] =
                acc[i][j] + boute[tx * 4 + j];
}

// ---------------------------------------------------------------------------
// CSR build: histogram over dst, single-block scan, scatter edge ids.
// ---------------------------------------------------------------------------
__global__ __launch_bounds__(256) void hist_kernel(
    const int* __restrict__ dst, int* __restrict__ hist)
{
    int i = blockIdx.x * 256 + threadIdx.x;
    if (i < EF) atomicAdd(&hist[dst[i]], 1);
}

__global__ __launch_bounds__(256) void scan_kernel(
    const int* __restrict__ hist, int* __restrict__ offs,
    int* __restrict__ cursor)
{
    __shared__ int sums[256];
    int tid = threadIdx.x;
    const int CH = 80;                     // 256*80 = 20480 >= NN
    int base = tid * CH;
    int local = 0;
    for (int i = 0; i < CH; ++i) {
        int idx = base + i;
        if (idx < NN) local += hist[idx];
    }
    sums[tid] = local;
    __syncthreads();
    for (int s = 1; s < 256; s <<= 1) {
        int v = (tid >= s) ? sums[tid - s] : 0;
        __syncthreads();
        sums[tid] += v;
        __syncthreads();
    }
    int run = sums[tid] - local;           // exclusive prefix
    for (int i = 0; i < CH; ++i) {
        int idx = base + i;
        if (idx < NN) {
            offs[idx] = run;
            cursor[idx] = run;
            run += hist[idx];
        }
    }
    if (tid == 255) offs[NN] = EF;
}

__global__ __launch_bounds__(256) void scatter_kernel(
    const int* __restrict__ dst, int* __restrict__ cursor,
    int* __restrict__ eid)
{
    int i = blockIdx.x * 256 + threadIdx.x;
    if (i < EF) {
        int p = atomicAdd(&cursor[dst[i]], 1);
        eid[p] = i;
    }
}

// ---------------------------------------------------------------------------
// CSR aggregation: one wave per node, no atomics. lane owns d=2*lane,2*lane+1
// (both in head lane>>3). 2-stage pipeline on the eid->src chain.
// ---------------------------------------------------------------------------
__global__ __launch_bounds__(256) void csr_aggregate(
    const float* __restrict__ V, const int* __restrict__ srcArr,
    const float* __restrict__ score, const int* __restrict__ offs,
    const int* __restrict__ eid, float* __restrict__ wV, float* __restrict__ z)
{
    int lane = threadIdx.x & 63;
    int wid = (blockIdx.x << 2) | (threadIdx.x >> 6);
    if (wid >= NN) return;
    int beg = offs[wid], end = offs[wid + 1];
    int hh = lane >> 3;

    float accx = 0.f, accy = 0.f, zacc = 0.f;
    int e_nxt = 0, s_nxt = 0;
    if (beg < end) { e_nxt = eid[beg]; s_nxt = srcArr[e_nxt]; }
    for (int p = beg; p < end; ++p) {
        int e = e_nxt, s = s_nxt;
        if (p + 1 < end) { e_nxt = eid[p + 1]; s_nxt = srcArr[e_nxt]; }
        float sc = score[e * 8 + hh];
        float2 v = *(const float2*)(V + (size_t)s * 128 + lane * 2);
        float s2 = __expf(fminf(fmaxf(sc, -5.f), 5.f));
        accx += v.x * s2;
        accy += v.y * s2;
        if (lane < 8) {
            float zs = score[e * 8 + lane];
            zacc += __expf(fminf(fmaxf(zs, -5.f), 5.f));
        }
    }
    float2 out = make_float2(accx, accy);
    *(float2*)(wV + (size_t)wid * 128 + lane * 2) = out;
    if (lane < 8) z[wid * 8 + lane] = zacc;
}

// ---------------------------------------------------------------------------
// h_out = (wV / (z + 1e-6)) @ Wout + bout.  Wave per node, Wout in LDS.
// ---------------------------------------------------------------------------
__global__ __launch_bounds__(256) void hout_kernel(
    const float* __restrict__ wV, const float* __restrict__ z,
    const float* __restrict__ Wout, const float* __restrict__ bout,
    float* __restrict__ out)
{
    __shared__ float Wl[128 * 128];
    for (int i = threadIdx.x; i < 4096; i += 256)
        ((float4*)Wl)[i] = ((const float4*)Wout)[i];
    __syncthreads();
    int lane = threadIdx.x & 63;
    int wid = (blockIdx.x << 2) | (threadIdx.x >> 6);
    int nw = gridDim.x << 2;
    for (int n = wid; n < NN; n += nw) {
        float z0 = z[n * 8 + (lane >> 4)] + 1e-6f;
        float z1 = z[n * 8 + 4 + (lane >> 4)] + 1e-6f;
        float w0 = wV[(size_t)n * 128 + lane] / z0;
        float w1 = wV[(size_t)n * 128 + 64 + lane] / z1;
        float acc0 = 0.f, acc1 = 0.f, acc0b = 0.f, acc1b = 0.f;
        #pragma unroll
        for (int k = 0; k < 64; ++k) {
            float b0 = __shfl(w0, k);
            acc0  += b0 * Wl[k * 128 + lane];
            acc1  += b0 * Wl[k * 128 + 64 + lane];
            float b1 = __shfl(w1, k);
            acc0b += b1 * Wl[(64 + k) * 128 + lane];
            acc1b += b1 * Wl[(64 + k) * 128 + 64 + lane];
        }
        out[(size_t)n * 128 + lane] = acc0 + acc0b + bout[lane];
        out[(size_t)n * 128 + 64 + lane] = acc1 + acc1b + bout[64 + lane];
    }
}

extern "C" void kernel_launch(void* const* d_in, const int* in_sizes, int n_in,
                              void* d_out, int out_size, void* d_ws, size_t ws_size,
                              hipStream_t stream)
{
    const float* h    = (const float*)d_in[0];
    const float* e    = (const float*)d_in[1];
    const float* adj2 = (const float*)d_in[2];
    const float* rel  = (const float*)d_in[3];
    const int*   src  = (const int*)d_in[4];
    const int*   dst  = (const int*)d_in[5];
    const int*   emap = (const int*)d_in[6];
    const float* Wq = (const float*)d_in[7];   const float* bq = (const float*)d_in[8];
    const float* Wk = (const float*)d_in[9];   const float* bk = (const float*)d_in[10];
    const float* Wv = (const float*)d_in[11];  const float* bv = (const float*)d_in[12];
    const float* Wpe = (const float*)d_in[13]; const float* bpe = (const float*)d_in[14];
    const float* Wap = (const float*)d_in[15]; const float* bap = (const float*)d_in[16];
    const float* Wout = (const float*)d_in[17]; const float* bout = (const float*)d_in[18];
    const float* Woute = (const float*)d_in[19]; const float* boute = (const float*)d_in[20];

    float* ws    = (float*)d_ws;
    float* Q     = ws;                 // 2,560,000 floats (dead after score_kernel)
    float* K     = ws + 2560000;
    float* V     = ws + 5120000;
    float* score = ws + 7680000;       // 5,120,000
    float* wV    = ws + 12800000;      // 2,560,000
    float* z     = ws + 15360000;      //   160,000
    float* h_out = (float*)d_out;
    float* e_out = (float*)d_out + 2560000;

    // CSR arrays alias Q's region (Q is dead after score_kernel; all CSR
    // kernels are stream-ordered after score_kernel).
    int* hist   = (int*)d_ws;          // 20,000
    int* offs   = (int*)d_ws + 20000;  // 20,001
    int* cursor = (int*)d_ws + 40001;  // 20,000
    int* eid    = (int*)d_ws + 60001;  // 640,000

    qkv_gemm<<<dim3(313, 6), 256, 0, stream>>>(h, Wq, bq, Wk, bk, Wv, bv, Q, K, V);
    score_kernel<<<20000, 256, 0, stream>>>(Q, K, src, dst, adj2, rel, score);
    gedge_a<<<1250, 256, 0, stream>>>(e, emap, Wpe, bpe, Wap, bap, score, e_out);
    eout_gemm<<<5000, 256, 0, stream>>>(e_out, Woute, boute);

    hipMemsetAsync(hist, 0, 20000 * sizeof(int), stream);
    hist_kernel<<<2500, 256, 0, stream>>>(dst, hist);
    scan_kernel<<<1, 256, 0, stream>>>(hist, offs, cursor);
    scatter_kernel<<<2500, 256, 0, stream>>>(dst, cursor, eid);
    csr_aggregate<<<5000, 256, 0, stream>>>(V, src, score, offs, eid, wV, z);

    hout_kernel<<<512, 256, 0, stream>>>(wV, z, Wout, bout, h_out);
}

// Round 3
// 476.334 us; speedup vs baseline: 1.4817x; 1.2502x over previous
//
#include <hip/hip_runtime.h>
#include <hip/hip_bf16.h>

#define NN 20000
#define EF 640000
#define EG 160000

// ---------------------------------------------------------------------------
// QKV: [20000,128] @ 128x128 (x3) -> Q,K,V  (grid.y selects Wq/Wk/Wv halves)
// ---------------------------------------------------------------------------
__global__ __launch_bounds__(256) void qkv_gemm(
    const float* __restrict__ h,
    const float* __restrict__ Wq, const float* __restrict__ bq,
    const float* __restrict__ Wk, const float* __restrict__ bk,
    const float* __restrict__ Wv, const float* __restrict__ bv,
    float* __restrict__ Qo, float* __restrict__ Ko, float* __restrict__ Vo)
{
    __shared__ float Al[64][68];
    __shared__ float Bl[64][68];
    const int bm = blockIdx.x;
    const int bsel = blockIdx.y;           // 0..5
    const float* W; const float* bias; float* Out;
    if (bsel < 2)      { W = Wq; bias = bq; Out = Qo; }
    else if (bsel < 4) { W = Wk; bias = bk; Out = Ko; }
    else               { W = Wv; bias = bv; Out = Vo; }
    const int col0 = (bsel & 1) * 64;
    const int tid = threadIdx.x;
    const int row0 = bm * 64;
    const int ty = tid >> 4, tx = tid & 15;

    float acc[4][4];
    #pragma unroll
    for (int i = 0; i < 4; ++i)
        #pragma unroll
        for (int j = 0; j < 4; ++j) acc[i][j] = 0.f;

    for (int kt = 0; kt < 2; ++kt) {
        if (kt) __syncthreads();
        #pragma unroll
        for (int i = 0; i < 4; ++i) {
            int f4 = tid + i * 256;
            int r = f4 >> 4, c = (f4 & 15) << 2;
            float4 v = make_float4(0.f, 0.f, 0.f, 0.f);
            int gr = row0 + r;
            if (gr < NN) v = *(const float4*)(h + (size_t)gr * 128 + kt * 64 + c);
            *(float4*)(&Al[r][c]) = v;
        }
        #pragma unroll
        for (int i = 0; i < 4; ++i) {
            int f4 = tid + i * 256;
            int r = f4 >> 4, c = (f4 & 15) << 2;
            float4 v = *(const float4*)(W + (size_t)(kt * 64 + r) * 128 + col0 + c);
            *(float4*)(&Bl[r][c]) = v;
        }
        __syncthreads();
        #pragma unroll
        for (int k = 0; k < 64; ++k) {
            float a[4];
            #pragma unroll
            for (int i = 0; i < 4; ++i) a[i] = Al[ty * 4 + i][k];
            float4 b4 = *(const float4*)(&Bl[k][tx * 4]);
            float b[4] = {b4.x, b4.y, b4.z, b4.w};
            #pragma unroll
            for (int i = 0; i < 4; ++i)
                #pragma unroll
                for (int j = 0; j < 4; ++j) acc[i][j] += a[i] * b[j];
        }
    }
    #pragma unroll
    for (int i = 0; i < 4; ++i) {
        int gr = row0 + ty * 4 + i;
        if (gr < NN) {
            #pragma unroll
            for (int j = 0; j < 4; ++j) {
                int c = col0 + tx * 4 + j;
                Out[(size_t)gr * 128 + c] = acc[i][j] + bias[c];
            }
        }
    }
}

// ---------------------------------------------------------------------------
// score1 for all full-graph edges: 8 lanes per edge (one per head)
// ---------------------------------------------------------------------------
__global__ __launch_bounds__(256) void score_kernel(
    const float* __restrict__ Q, const float* __restrict__ K,
    const int* __restrict__ src, const int* __restrict__ dst,
    const float* __restrict__ adj2, const float* __restrict__ rel,
    float* __restrict__ score)
{
    int tid = blockIdx.x * 256 + threadIdx.x;   // over EF*8 = 5,120,000
    if (tid >= EF * 8) return;
    int e = tid >> 3, hh = tid & 7;
    int s = src[e], d = dst[e];
    const float4* Kp = (const float4*)(K + (size_t)s * 128 + hh * 16);
    const float4* Qp = (const float4*)(Q + (size_t)d * 128 + hh * 16);
    float dot = 0.f;
    #pragma unroll
    for (int j = 0; j < 4; ++j) {
        float4 a = Kp[j]; float4 b = Qp[j];
        dot += a.x * b.x + a.y * b.y + a.z * b.z + a.w * b.w;
    }
    dot *= 0.25f;  // / sqrt(16)
    float sc = __expf(fminf(fmaxf(dot, -5.f), 5.f) * adj2[e]) + rel[e];
    score[tid] = sc;
}

// ---------------------------------------------------------------------------
// g-edge pipeline (one wave per g-edge). Weights hoisted to registers;
// proj_e reduce = recursive halving (4+2+1 shfl) + 3-shfl butterfly + 1 gather.
// Lane owns e-cols 2*lane, 2*lane+1.
// ---------------------------------------------------------------------------
__global__ __launch_bounds__(256) void gedge_a(
    const float* __restrict__ efeat, const int* __restrict__ emap,
    const float* __restrict__ Wpe, const float* __restrict__ bpe,
    const float* __restrict__ Wap, const float* __restrict__ bap,
    float* __restrict__ score, float* __restrict__ tmp)
{
    int lane = threadIdx.x & 63;
    int wid = (blockIdx.x << 2) | (threadIdx.x >> 6);
    int nw = gridDim.x << 2;

    // hoisted per-lane weights (loop-invariant)
    float wpe0[8], wpe1[8], wap0[8], wap1[8];
    #pragma unroll
    for (int hh = 0; hh < 8; ++hh) {
        wpe0[hh] = Wpe[(2 * lane) * 8 + hh];
        wpe1[hh] = Wpe[(2 * lane + 1) * 8 + hh];
        wap0[hh] = Wap[hh * 128 + 2 * lane];
        wap1[hh] = Wap[hh * 128 + 2 * lane + 1];
    }
    float bap0 = bap[2 * lane], bap1 = bap[2 * lane + 1];
    float bpe_l = bpe[lane & 7];

    const int b2 = (lane >> 5) & 1;
    const int b1 = (lane >> 4) & 1;
    const int b0 = (lane >> 3) & 1;

    for (int i = wid; i < EG; i += nw) {
        int fidx = __builtin_amdgcn_readfirstlane(emap[i]);
        float gs[8];
        #pragma unroll
        for (int hh = 0; hh < 8; ++hh) gs[hh] = score[fidx * 8 + hh];
        float2 ev = ((const float2*)efeat)[(size_t)i * 64 + lane];

        float p[8];
        #pragma unroll
        for (int hh = 0; hh < 8; ++hh)
            p[hh] = ev.x * wpe0[hh] + ev.y * wpe1[hh];

        // reduce-scatter over lane bits 5,4,3 (value-index bits 2,1,0)
        float q[4];
        #pragma unroll
        for (int j = 0; j < 4; ++j) {
            float send = b2 ? p[j] : p[4 + j];
            float recv = __shfl_xor(send, 32);
            q[j] = (b2 ? p[4 + j] : p[j]) + recv;
        }
        float r2[2];
        #pragma unroll
        for (int j = 0; j < 2; ++j) {
            float send = b1 ? q[j] : q[2 + j];
            float recv = __shfl_xor(send, 16);
            r2[j] = (b1 ? q[2 + j] : q[j]) + recv;
        }
        {
            float send = b0 ? r2[0] : r2[1];
            float recv = __shfl_xor(send, 8);
            r2[0] = (b0 ? r2[1] : r2[0]) + recv;
        }
        // now lane l holds partial sum of p[l>>3] over lanes sharing (l&7)
        float s = r2[0];
        s += __shfl_xor(s, 4);
        s += __shfl_xor(s, 2);
        s += __shfl_xor(s, 1);
        // every lane: total sum of p[lane>>3]; gather head (lane&7)
        float ph = __shfl(s, (lane & 7) * 8);

        // lanes 0..7 update score row (gv = gs[lane] via select chain)
        float gv = gs[0];
        #pragma unroll
        for (int hh = 1; hh < 8; ++hh) gv = (lane == hh) ? gs[hh] : gv;
        if (lane < 8)
            score[fidx * 8 + lane] = fminf(fmaxf(gv, -5.f), 5.f) + bpe_l + ph;

        // attention projection + residual e
        float ap0 = bap0, ap1 = bap1;
        #pragma unroll
        for (int hh = 0; hh < 8; ++hh) {
            ap0 += gs[hh] * wap0[hh];
            ap1 += gs[hh] * wap1[hh];
        }
        ((float2*)tmp)[(size_t)i * 64 + lane] = make_float2(ap0 + ev.x, ap1 + ev.y);
    }
}

// ---------------------------------------------------------------------------
// e_out = tmp @ Woute + boute, in place on d_out e-section.
// ---------------------------------------------------------------------------
__global__ __launch_bounds__(256) void eout_gemm(
    float* __restrict__ io, const float* __restrict__ Woute,
    const float* __restrict__ boute)
{
    __shared__ float Al[32][132];
    __shared__ float Bl[64][132];
    const int row0 = blockIdx.x * 32;
    const int tid = threadIdx.x;
    const int ty = tid >> 5, tx = tid & 31;   // 8 x 32

    #pragma unroll
    for (int i = 0; i < 4; ++i) {
        int f4 = tid + i * 256;
        int r = f4 >> 5, c = (f4 & 31) << 2;
        *(float4*)(&Al[r][c]) = *(const float4*)(io + (size_t)(row0 + r) * 128 + c);
    }
    float acc[4][4];
    #pragma unroll
    for (int i = 0; i < 4; ++i)
        #pragma unroll
        for (int j = 0; j < 4; ++j) acc[i][j] = 0.f;

    for (int kt = 0; kt < 2; ++kt) {
        if (kt) __syncthreads();
        #pragma unroll
        for (int i = 0; i < 8; ++i) {
            int f4 = tid + i * 256;
            int r = f4 >> 5, c = (f4 & 31) << 2;
            *(float4*)(&Bl[r][c]) = *(const float4*)(Woute + (size_t)(kt * 64 + r) * 128 + c);
        }
        __syncthreads();
        #pragma unroll
        for (int k = 0; k < 64; ++k) {
            float a[4];
            #pragma unroll
            for (int i = 0; i < 4; ++i) a[i] = Al[ty * 4 + i][kt * 64 + k];
            float4 b4 = *(const float4*)(&Bl[k][tx * 4]);
            float b[4] = {b4.x, b4.y, b4.z, b4.w};
            #pragma unroll
            for (int i = 0; i < 4; ++i)
                #pragma unroll
                for (int j = 0; j < 4; ++j) acc[i][j] += a[i] * b[j];
        }
    }
    #pragma unroll
    for (int i = 0; i < 4; ++i)
        #pragma unroll
        for (int j = 0; j < 4; ++j)
            io[(size_t)(row0 + ty * 4 + i) * 128 + tx * 4 + j] =
                acc[i][j] + boute[tx * 4 + j];
}

// ---------------------------------------------------------------------------
// CSR build: histogram over dst, single-block scan, scatter edge ids.
// ---------------------------------------------------------------------------
__global__ __launch_bounds__(256) void hist_kernel(
    const int* __restrict__ dst, int* __restrict__ hist)
{
    int i = blockIdx.x * 256 + threadIdx.x;
    if (i < EF) atomicAdd(&hist[dst[i]], 1);
}

__global__ __launch_bounds__(256) void scan_kernel(
    const int* __restrict__ hist, int* __restrict__ offs,
    int* __restrict__ cursor)
{
    __shared__ int sums[256];
    int tid = threadIdx.x;
    const int CH = 80;                     // 256*80 = 20480 >= NN
    int base = tid * CH;
    int local = 0;
    for (int i = 0; i < CH; ++i) {
        int idx = base + i;
        if (idx < NN) local += hist[idx];
    }
    sums[tid] = local;
    __syncthreads();
    for (int s = 1; s < 256; s <<= 1) {
        int v = (tid >= s) ? sums[tid - s] : 0;
        __syncthreads();
        sums[tid] += v;
        __syncthreads();
    }
    int run = sums[tid] - local;           // exclusive prefix
    for (int i = 0; i < CH; ++i) {
        int idx = base + i;
        if (idx < NN) {
            offs[idx] = run;
            cursor[idx] = run;
            run += hist[idx];
        }
    }
    if (tid == 255) offs[NN] = EF;
}

__global__ __launch_bounds__(256) void scatter_kernel(
    const int* __restrict__ dst, int* __restrict__ cursor,
    int* __restrict__ eid)
{
    int i = blockIdx.x * 256 + threadIdx.x;
    if (i < EF) {
        int p = atomicAdd(&cursor[dst[i]], 1);
        eid[p] = i;
    }
}

// ---------------------------------------------------------------------------
// CSR aggregation: one wave per node, no atomics.
// ---------------------------------------------------------------------------
__global__ __launch_bounds__(256) void csr_aggregate(
    const float* __restrict__ V, const int* __restrict__ srcArr,
    const float* __restrict__ score, const int* __restrict__ offs,
    const int* __restrict__ eid, float* __restrict__ wV, float* __restrict__ z)
{
    int lane = threadIdx.x & 63;
    int wid = (blockIdx.x << 2) | (threadIdx.x >> 6);
    if (wid >= NN) return;
    int beg = offs[wid], end = offs[wid + 1];
    int hh = lane >> 3;

    float accx = 0.f, accy = 0.f, zacc = 0.f;
    int e_nxt = 0, s_nxt = 0;
    if (beg < end) { e_nxt = eid[beg]; s_nxt = srcArr[e_nxt]; }
    for (int p = beg; p < end; ++p) {
        int e = e_nxt, s = s_nxt;
        if (p + 1 < end) { e_nxt = eid[p + 1]; s_nxt = srcArr[e_nxt]; }
        float sc = score[e * 8 + hh];
        float2 v = *(const float2*)(V + (size_t)s * 128 + lane * 2);
        float s2 = __expf(fminf(fmaxf(sc, -5.f), 5.f));
        accx += v.x * s2;
        accy += v.y * s2;
        if (lane < 8) {
            float zs = score[e * 8 + lane];
            zacc += __expf(fminf(fmaxf(zs, -5.f), 5.f));
        }
    }
    *(float2*)(wV + (size_t)wid * 128 + lane * 2) = make_float2(accx, accy);
    if (lane < 8) z[wid * 8 + lane] = zacc;
}

// ---------------------------------------------------------------------------
// h_out = (wV / (z+1e-6)) @ Wout + bout as a tiled GEMM; normalization fused
// into the A-tile load (each float4 of a wV row lies within one head group).
// ---------------------------------------------------------------------------
__global__ __launch_bounds__(256) void hout_gemm(
    const float* __restrict__ wV, const float* __restrict__ z,
    const float* __restrict__ Wout, const float* __restrict__ bout,
    float* __restrict__ out)
{
    __shared__ float Al[64][68];
    __shared__ float Bl[64][68];
    const int row0 = blockIdx.x * 64;
    const int col0 = blockIdx.y * 64;
    const int tid = threadIdx.x;
    const int ty = tid >> 4, tx = tid & 15;

    float acc[4][4];
    #pragma unroll
    for (int i = 0; i < 4; ++i)
        #pragma unroll
        for (int j = 0; j < 4; ++j) acc[i][j] = 0.f;

    for (int kt = 0; kt < 2; ++kt) {
        if (kt) __syncthreads();
        #pragma unroll
        for (int i = 0; i < 4; ++i) {
            int f4 = tid + i * 256;
            int r = f4 >> 4, c = (f4 & 15) << 2;
            float4 v = make_float4(0.f, 0.f, 0.f, 0.f);
            int gr = row0 + r;
            if (gr < NN) {
                v = *(const float4*)(wV + (size_t)gr * 128 + kt * 64 + c);
                float rz = 1.f / (z[gr * 8 + ((kt * 64 + c) >> 4)] + 1e-6f);
                v.x *= rz; v.y *= rz; v.z *= rz; v.w *= rz;
            }
            *(float4*)(&Al[r][c]) = v;
        }
        #pragma unroll
        for (int i = 0; i < 4; ++i) {
            int f4 = tid + i * 256;
            int r = f4 >> 4, c = (f4 & 15) << 2;
            float4 v = *(const float4*)(Wout + (size_t)(kt * 64 + r) * 128 + col0 + c);
            *(float4*)(&Bl[r][c]) = v;
        }
        __syncthreads();
        #pragma unroll
        for (int k = 0; k < 64; ++k) {
            float a[4];
            #pragma unroll
            for (int i = 0; i < 4; ++i) a[i] = Al[ty * 4 + i][k];
            float4 b4 = *(const float4*)(&Bl[k][tx * 4]);
            float b[4] = {b4.x, b4.y, b4.z, b4.w};
            #pragma unroll
            for (int i = 0; i < 4; ++i)
                #pragma unroll
                for (int j = 0; j < 4; ++j) acc[i][j] += a[i] * b[j];
        }
    }
    #pragma unroll
    for (int i = 0; i < 4; ++i) {
        int gr = row0 + ty * 4 + i;
        if (gr < NN) {
            #pragma unroll
            for (int j = 0; j < 4; ++j) {
                int c = col0 + tx * 4 + j;
                out[(size_t)gr * 128 + c] = acc[i][j] + bout[c];
            }
        }
    }
}

extern "C" void kernel_launch(void* const* d_in, const int* in_sizes, int n_in,
                              void* d_out, int out_size, void* d_ws, size_t ws_size,
                              hipStream_t stream)
{
    const float* h    = (const float*)d_in[0];
    const float* e    = (const float*)d_in[1];
    const float* adj2 = (const float*)d_in[2];
    const float* rel  = (const float*)d_in[3];
    const int*   src  = (const int*)d_in[4];
    const int*   dst  = (const int*)d_in[5];
    const int*   emap = (const int*)d_in[6];
    const float* Wq = (const float*)d_in[7];   const float* bq = (const float*)d_in[8];
    const float* Wk = (const float*)d_in[9];   const float* bk = (const float*)d_in[10];
    const float* Wv = (const float*)d_in[11];  const float* bv = (const float*)d_in[12];
    const float* Wpe = (const float*)d_in[13]; const float* bpe = (const float*)d_in[14];
    const float* Wap = (const float*)d_in[15]; const float* bap = (const float*)d_in[16];
    const float* Wout = (const float*)d_in[17]; const float* bout = (const float*)d_in[18];
    const float* Woute = (const float*)d_in[19]; const float* boute = (const float*)d_in[20];

    float* ws    = (float*)d_ws;
    float* Q     = ws;                 // 2,560,000 floats (dead after score_kernel)
    float* K     = ws + 2560000;
    float* V     = ws + 5120000;
    float* score = ws + 7680000;       // 5,120,000
    float* wV    = ws + 12800000;      // 2,560,000
    float* z     = ws + 15360000;      //   160,000
    float* h_out = (float*)d_out;
    float* e_out = (float*)d_out + 2560000;

    // CSR arrays alias Q's region (Q is dead after score_kernel).
    int* hist   = (int*)d_ws;          // 20,000
    int* offs   = (int*)d_ws + 20000;  // 20,001
    int* cursor = (int*)d_ws + 40001;  // 20,000
    int* eid    = (int*)d_ws + 60001;  // 640,000

    qkv_gemm<<<dim3(313, 6), 256, 0, stream>>>(h, Wq, bq, Wk, bk, Wv, bv, Q, K, V);
    score_kernel<<<20000, 256, 0, stream>>>(Q, K, src, dst, adj2, rel, score);
    gedge_a<<<1250, 256, 0, stream>>>(e, emap, Wpe, bpe, Wap, bap, score, e_out);
    eout_gemm<<<5000, 256, 0, stream>>>(e_out, Woute, boute);

    hipMemsetAsync(hist, 0, 20000 * sizeof(int), stream);
    hist_kernel<<<2500, 256, 0, stream>>>(dst, hist);
    scan_kernel<<<1, 256, 0, stream>>>(hist, offs, cursor);
    scatter_kernel<<<2500, 256, 0, stream>>>(dst, cursor, eid);
    csr_aggregate<<<5000, 256, 0, stream>>>(V, src, score, offs, eid, wV, z);

    hout_gemm<<<dim3(313, 2), 256, 0, stream>>>(wV, z, Wout, bout, h_out);
}

// Round 4
// 449.013 us; speedup vs baseline: 1.5718x; 1.0608x over previous
//
#include <hip/hip_runtime.h>
#include <hip/hip_bf16.h>

#define NN 20000
#define EF 640000
#define EG 160000

// ---------------------------------------------------------------------------
// QKV: [20000,128] @ 128x128 (x3) -> Q,K,V  (grid.y selects Wq/Wk/Wv halves)
// ---------------------------------------------------------------------------
__global__ __launch_bounds__(256) void qkv_gemm(
    const float* __restrict__ h,
    const float* __restrict__ Wq, const float* __restrict__ bq,
    const float* __restrict__ Wk, const float* __restrict__ bk,
    const float* __restrict__ Wv, const float* __restrict__ bv,
    float* __restrict__ Qo, float* __restrict__ Ko, float* __restrict__ Vo)
{
    __shared__ float Al[64][68];
    __shared__ float Bl[64][68];
    const int bm = blockIdx.x;
    const int bsel = blockIdx.y;           // 0..5
    const float* W; const float* bias; float* Out;
    if (bsel < 2)      { W = Wq; bias = bq; Out = Qo; }
    else if (bsel < 4) { W = Wk; bias = bk; Out = Ko; }
    else               { W = Wv; bias = bv; Out = Vo; }
    const int col0 = (bsel & 1) * 64;
    const int tid = threadIdx.x;
    const int row0 = bm * 64;
    const int ty = tid >> 4, tx = tid & 15;

    float acc[4][4];
    #pragma unroll
    for (int i = 0; i < 4; ++i)
        #pragma unroll
        for (int j = 0; j < 4; ++j) acc[i][j] = 0.f;

    for (int kt = 0; kt < 2; ++kt) {
        if (kt) __syncthreads();
        #pragma unroll
        for (int i = 0; i < 4; ++i) {
            int f4 = tid + i * 256;
            int r = f4 >> 4, c = (f4 & 15) << 2;
            float4 v = make_float4(0.f, 0.f, 0.f, 0.f);
            int gr = row0 + r;
            if (gr < NN) v = *(const float4*)(h + (size_t)gr * 128 + kt * 64 + c);
            *(float4*)(&Al[r][c]) = v;
        }
        #pragma unroll
        for (int i = 0; i < 4; ++i) {
            int f4 = tid + i * 256;
            int r = f4 >> 4, c = (f4 & 15) << 2;
            float4 v = *(const float4*)(W + (size_t)(kt * 64 + r) * 128 + col0 + c);
            *(float4*)(&Bl[r][c]) = v;
        }
        __syncthreads();
        #pragma unroll
        for (int k = 0; k < 64; ++k) {
            float a[4];
            #pragma unroll
            for (int i = 0; i < 4; ++i) a[i] = Al[ty * 4 + i][k];
            float4 b4 = *(const float4*)(&Bl[k][tx * 4]);
            float b[4] = {b4.x, b4.y, b4.z, b4.w};
            #pragma unroll
            for (int i = 0; i < 4; ++i)
                #pragma unroll
                for (int j = 0; j < 4; ++j) acc[i][j] += a[i] * b[j];
        }
    }
    #pragma unroll
    for (int i = 0; i < 4; ++i) {
        int gr = row0 + ty * 4 + i;
        if (gr < NN) {
            #pragma unroll
            for (int j = 0; j < 4; ++j) {
                int c = col0 + tx * 4 + j;
                Out[(size_t)gr * 128 + c] = acc[i][j] + bias[c];
            }
        }
    }
}

// ---------------------------------------------------------------------------
// score1 for all full-graph edges: 8 lanes per edge (one per head)
// ---------------------------------------------------------------------------
__global__ __launch_bounds__(256) void score_kernel(
    const float* __restrict__ Q, const float* __restrict__ K,
    const int* __restrict__ src, const int* __restrict__ dst,
    const float* __restrict__ adj2, const float* __restrict__ rel,
    float* __restrict__ score)
{
    int tid = blockIdx.x * 256 + threadIdx.x;   // over EF*8 = 5,120,000
    if (tid >= EF * 8) return;
    int e = tid >> 3, hh = tid & 7;
    int s = src[e], d = dst[e];
    const float4* Kp = (const float4*)(K + (size_t)s * 128 + hh * 16);
    const float4* Qp = (const float4*)(Q + (size_t)d * 128 + hh * 16);
    float dot = 0.f;
    #pragma unroll
    for (int j = 0; j < 4; ++j) {
        float4 a = Kp[j]; float4 b = Qp[j];
        dot += a.x * b.x + a.y * b.y + a.z * b.z + a.w * b.w;
    }
    dot *= 0.25f;  // / sqrt(16)
    float sc = __expf(fminf(fmaxf(dot, -5.f), 5.f) * adj2[e]) + rel[e];
    score[tid] = sc;
}

// ---------------------------------------------------------------------------
// g-edge pipeline (one wave per g-edge). Weights hoisted to registers.
// ---------------------------------------------------------------------------
__global__ __launch_bounds__(256) void gedge_a(
    const float* __restrict__ efeat, const int* __restrict__ emap,
    const float* __restrict__ Wpe, const float* __restrict__ bpe,
    const float* __restrict__ Wap, const float* __restrict__ bap,
    float* __restrict__ score, float* __restrict__ tmp)
{
    int lane = threadIdx.x & 63;
    int wid = (blockIdx.x << 2) | (threadIdx.x >> 6);
    int nw = gridDim.x << 2;

    float wpe0[8], wpe1[8], wap0[8], wap1[8];
    #pragma unroll
    for (int hh = 0; hh < 8; ++hh) {
        wpe0[hh] = Wpe[(2 * lane) * 8 + hh];
        wpe1[hh] = Wpe[(2 * lane + 1) * 8 + hh];
        wap0[hh] = Wap[hh * 128 + 2 * lane];
        wap1[hh] = Wap[hh * 128 + 2 * lane + 1];
    }
    float bap0 = bap[2 * lane], bap1 = bap[2 * lane + 1];
    float bpe_l = bpe[lane & 7];

    const int b2 = (lane >> 5) & 1;
    const int b1 = (lane >> 4) & 1;
    const int b0 = (lane >> 3) & 1;

    for (int i = wid; i < EG; i += nw) {
        int fidx = __builtin_amdgcn_readfirstlane(emap[i]);
        float gs[8];
        #pragma unroll
        for (int hh = 0; hh < 8; ++hh) gs[hh] = score[fidx * 8 + hh];
        float2 ev = ((const float2*)efeat)[(size_t)i * 64 + lane];

        float p[8];
        #pragma unroll
        for (int hh = 0; hh < 8; ++hh)
            p[hh] = ev.x * wpe0[hh] + ev.y * wpe1[hh];

        float q[4];
        #pragma unroll
        for (int j = 0; j < 4; ++j) {
            float send = b2 ? p[j] : p[4 + j];
            float recv = __shfl_xor(send, 32);
            q[j] = (b2 ? p[4 + j] : p[j]) + recv;
        }
        float r2[2];
        #pragma unroll
        for (int j = 0; j < 2; ++j) {
            float send = b1 ? q[j] : q[2 + j];
            float recv = __shfl_xor(send, 16);
            r2[j] = (b1 ? q[2 + j] : q[j]) + recv;
        }
        {
            float send = b0 ? r2[0] : r2[1];
            float recv = __shfl_xor(send, 8);
            r2[0] = (b0 ? r2[1] : r2[0]) + recv;
        }
        float s = r2[0];
        s += __shfl_xor(s, 4);
        s += __shfl_xor(s, 2);
        s += __shfl_xor(s, 1);
        float ph = __shfl(s, (lane & 7) * 8);

        float gv = gs[0];
        #pragma unroll
        for (int hh = 1; hh < 8; ++hh) gv = (lane == hh) ? gs[hh] : gv;
        if (lane < 8)
            score[fidx * 8 + lane] = fminf(fmaxf(gv, -5.f), 5.f) + bpe_l + ph;

        float ap0 = bap0, ap1 = bap1;
        #pragma unroll
        for (int hh = 0; hh < 8; ++hh) {
            ap0 += gs[hh] * wap0[hh];
            ap1 += gs[hh] * wap1[hh];
        }
        ((float2*)tmp)[(size_t)i * 64 + lane] = make_float2(ap0 + ev.x, ap1 + ev.y);
    }
}

// ---------------------------------------------------------------------------
// in-place exp(clip(score)) over all EF*8 scores, float4-vectorized
// ---------------------------------------------------------------------------
__global__ __launch_bounds__(256) void exp_kernel(float* __restrict__ score)
{
    int i = blockIdx.x * 256 + threadIdx.x;     // over 1,280,000 float4
    if (i >= EF * 2) return;
    float4 v = ((float4*)score)[i];
    v.x = __expf(fminf(fmaxf(v.x, -5.f), 5.f));
    v.y = __expf(fminf(fmaxf(v.y, -5.f), 5.f));
    v.z = __expf(fminf(fmaxf(v.z, -5.f), 5.f));
    v.w = __expf(fminf(fmaxf(v.w, -5.f), 5.f));
    ((float4*)score)[i] = v;
}

// ---------------------------------------------------------------------------
// e_out = tmp @ Woute + boute, in place on d_out e-section.
// ---------------------------------------------------------------------------
__global__ __launch_bounds__(256) void eout_gemm(
    float* __restrict__ io, const float* __restrict__ Woute,
    const float* __restrict__ boute)
{
    __shared__ float Al[32][132];
    __shared__ float Bl[64][132];
    const int row0 = blockIdx.x * 32;
    const int tid = threadIdx.x;
    const int ty = tid >> 5, tx = tid & 31;   // 8 x 32

    #pragma unroll
    for (int i = 0; i < 4; ++i) {
        int f4 = tid + i * 256;
        int r = f4 >> 5, c = (f4 & 31) << 2;
        *(float4*)(&Al[r][c]) = *(const float4*)(io + (size_t)(row0 + r) * 128 + c);
    }
    float acc[4][4];
    #pragma unroll
    for (int i = 0; i < 4; ++i)
        #pragma unroll
        for (int j = 0; j < 4; ++j) acc[i][j] = 0.f;

    for (int kt = 0; kt < 2; ++kt) {
        if (kt) __syncthreads();
        #pragma unroll
        for (int i = 0; i < 8; ++i) {
            int f4 = tid + i * 256;
            int r = f4 >> 5, c = (f4 & 31) << 2;
            *(float4*)(&Bl[r][c]) = *(const float4*)(Woute + (size_t)(kt * 64 + r) * 128 + c);
        }
        __syncthreads();
        #pragma unroll
        for (int k = 0; k < 64; ++k) {
            float a[4];
            #pragma unroll
            for (int i = 0; i < 4; ++i) a[i] = Al[ty * 4 + i][kt * 64 + k];
            float4 b4 = *(const float4*)(&Bl[k][tx * 4]);
            float b[4] = {b4.x, b4.y, b4.z, b4.w};
            #pragma unroll
            for (int i = 0; i < 4; ++i)
                #pragma unroll
                for (int j = 0; j < 4; ++j) acc[i][j] += a[i] * b[j];
        }
    }
    #pragma unroll
    for (int i = 0; i < 4; ++i)
        #pragma unroll
        for (int j = 0; j < 4; ++j)
            io[(size_t)(row0 + ty * 4 + i) * 128 + tx * 4 + j] =
                acc[i][j] + boute[tx * 4 + j];
}

// ---------------------------------------------------------------------------
// CSR build: histogram over dst, single-block scan, scatter edge ids.
// ---------------------------------------------------------------------------
__global__ __launch_bounds__(256) void hist_kernel(
    const int* __restrict__ dst, int* __restrict__ hist)
{
    int i = blockIdx.x * 256 + threadIdx.x;
    if (i < EF) atomicAdd(&hist[dst[i]], 1);
}

__global__ __launch_bounds__(256) void scan_kernel(
    const int* __restrict__ hist, int* __restrict__ offs,
    int* __restrict__ cursor)
{
    __shared__ int sums[256];
    int tid = threadIdx.x;
    const int CH = 80;                     // 256*80 = 20480 >= NN
    int base = tid * CH;
    int local = 0;
    for (int i = 0; i < CH; ++i) {
        int idx = base + i;
        if (idx < NN) local += hist[idx];
    }
    sums[tid] = local;
    __syncthreads();
    for (int s = 1; s < 256; s <<= 1) {
        int v = (tid >= s) ? sums[tid - s] : 0;
        __syncthreads();
        sums[tid] += v;
        __syncthreads();
    }
    int run = sums[tid] - local;           // exclusive prefix
    for (int i = 0; i < CH; ++i) {
        int idx = base + i;
        if (idx < NN) {
            offs[idx] = run;
            cursor[idx] = run;
            run += hist[idx];
        }
    }
    if (tid == 255) offs[NN] = EF;
}

__global__ __launch_bounds__(256) void scatter_kernel(
    const int* __restrict__ dst, int* __restrict__ cursor,
    int* __restrict__ eid)
{
    int i = blockIdx.x * 256 + threadIdx.x;
    if (i < EF) {
        int p = atomicAdd(&cursor[dst[i]], 1);
        eid[p] = i;
    }
}

// ---------------------------------------------------------------------------
// CSR aggregation: one wave per node, no atomics, exp pre-applied.
// Unroll-4 for memory-level parallelism. z falls out of the sc stream
// (all 8 lanes of a head group hold the same sc; lane (hh*8) writes z).
// ---------------------------------------------------------------------------
__global__ __launch_bounds__(256) void csr_aggregate(
    const float* __restrict__ V, const int* __restrict__ srcArr,
    const float* __restrict__ score, const int* __restrict__ offs,
    const int* __restrict__ eid, float* __restrict__ wV, float* __restrict__ z)
{
    int lane = threadIdx.x & 63;
    int wid = (blockIdx.x << 2) | (threadIdx.x >> 6);
    if (wid >= NN) return;
    int beg = offs[wid], end = offs[wid + 1];
    int hh = lane >> 3;

    float accx = 0.f, accy = 0.f, zacc = 0.f;
    int p = beg;
    for (; p + 4 <= end; p += 4) {
        int e0 = eid[p],     e1 = eid[p + 1];
        int e2 = eid[p + 2], e3 = eid[p + 3];
        int s0 = srcArr[e0], s1 = srcArr[e1];
        int s2 = srcArr[e2], s3 = srcArr[e3];
        float sc0 = score[e0 * 8 + hh];
        float sc1 = score[e1 * 8 + hh];
        float sc2 = score[e2 * 8 + hh];
        float sc3 = score[e3 * 8 + hh];
        float2 v0 = *(const float2*)(V + (size_t)s0 * 128 + lane * 2);
        float2 v1 = *(const float2*)(V + (size_t)s1 * 128 + lane * 2);
        float2 v2 = *(const float2*)(V + (size_t)s2 * 128 + lane * 2);
        float2 v3 = *(const float2*)(V + (size_t)s3 * 128 + lane * 2);
        accx += v0.x * sc0; accy += v0.y * sc0;
        accx += v1.x * sc1; accy += v1.y * sc1;
        accx += v2.x * sc2; accy += v2.y * sc2;
        accx += v3.x * sc3; accy += v3.y * sc3;
        zacc += (sc0 + sc1) + (sc2 + sc3);
    }
    for (; p < end; ++p) {
        int e = eid[p];
        int s = srcArr[e];
        float sc = score[e * 8 + hh];
        float2 v = *(const float2*)(V + (size_t)s * 128 + lane * 2);
        accx += v.x * sc; accy += v.y * sc;
        zacc += sc;
    }
    *(float2*)(wV + (size_t)wid * 128 + lane * 2) = make_float2(accx, accy);
    if ((lane & 7) == 0) z[wid * 8 + hh] = zacc;
}

// ---------------------------------------------------------------------------
// h_out = (wV / (z+1e-6)) @ Wout + bout as a tiled GEMM; normalization fused
// into the A-tile load.
// ---------------------------------------------------------------------------
__global__ __launch_bounds__(256) void hout_gemm(
    const float* __restrict__ wV, const float* __restrict__ z,
    const float* __restrict__ Wout, const float* __restrict__ bout,
    float* __restrict__ out)
{
    __shared__ float Al[64][68];
    __shared__ float Bl[64][68];
    const int row0 = blockIdx.x * 64;
    const int col0 = blockIdx.y * 64;
    const int tid = threadIdx.x;
    const int ty = tid >> 4, tx = tid & 15;

    float acc[4][4];
    #pragma unroll
    for (int i = 0; i < 4; ++i)
        #pragma unroll
        for (int j = 0; j < 4; ++j) acc[i][j] = 0.f;

    for (int kt = 0; kt < 2; ++kt) {
        if (kt) __syncthreads();
        #pragma unroll
        for (int i = 0; i < 4; ++i) {
            int f4 = tid + i * 256;
            int r = f4 >> 4, c = (f4 & 15) << 2;
            float4 v = make_float4(0.f, 0.f, 0.f, 0.f);
            int gr = row0 + r;
            if (gr < NN) {
                v = *(const float4*)(wV + (size_t)gr * 128 + kt * 64 + c);
                float rz = 1.f / (z[gr * 8 + ((kt * 64 + c) >> 4)] + 1e-6f);
                v.x *= rz; v.y *= rz; v.z *= rz; v.w *= rz;
            }
            *(float4*)(&Al[r][c]) = v;
        }
        #pragma unroll
        for (int i = 0; i < 4; ++i) {
            int f4 = tid + i * 256;
            int r = f4 >> 4, c = (f4 & 15) << 2;
            float4 v = *(const float4*)(Wout + (size_t)(kt * 64 + r) * 128 + col0 + c);
            *(float4*)(&Bl[r][c]) = v;
        }
        __syncthreads();
        #pragma unroll
        for (int k = 0; k < 64; ++k) {
            float a[4];
            #pragma unroll
            for (int i = 0; i < 4; ++i) a[i] = Al[ty * 4 + i][k];
            float4 b4 = *(const float4*)(&Bl[k][tx * 4]);
            float b[4] = {b4.x, b4.y, b4.z, b4.w};
            #pragma unroll
            for (int i = 0; i < 4; ++i)
                #pragma unroll
                for (int j = 0; j < 4; ++j) acc[i][j] += a[i] * b[j];
        }
    }
    #pragma unroll
    for (int i = 0; i < 4; ++i) {
        int gr = row0 + ty * 4 + i;
        if (gr < NN) {
            #pragma unroll
            for (int j = 0; j < 4; ++j) {
                int c = col0 + tx * 4 + j;
                out[(size_t)gr * 128 + c] = acc[i][j] + bout[c];
            }
        }
    }
}

extern "C" void kernel_launch(void* const* d_in, const int* in_sizes, int n_in,
                              void* d_out, int out_size, void* d_ws, size_t ws_size,
                              hipStream_t stream)
{
    const float* h    = (const float*)d_in[0];
    const float* e    = (const float*)d_in[1];
    const float* adj2 = (const float*)d_in[2];
    const float* rel  = (const float*)d_in[3];
    const int*   src  = (const int*)d_in[4];
    const int*   dst  = (const int*)d_in[5];
    const int*   emap = (const int*)d_in[6];
    const float* Wq = (const float*)d_in[7];   const float* bq = (const float*)d_in[8];
    const float* Wk = (const float*)d_in[9];   const float* bk = (const float*)d_in[10];
    const float* Wv = (const float*)d_in[11];  const float* bv = (const float*)d_in[12];
    const float* Wpe = (const float*)d_in[13]; const float* bpe = (const float*)d_in[14];
    const float* Wap = (const float*)d_in[15]; const float* bap = (const float*)d_in[16];
    const float* Wout = (const float*)d_in[17]; const float* bout = (const float*)d_in[18];
    const float* Woute = (const float*)d_in[19]; const float* boute = (const float*)d_in[20];

    float* ws    = (float*)d_ws;
    float* Q     = ws;                 // 2,560,000 floats (dead after score_kernel)
    float* K     = ws + 2560000;
    float* V     = ws + 5120000;
    float* score = ws + 7680000;       // 5,120,000
    float* wV    = ws + 12800000;      // 2,560,000
    float* z     = ws + 15360000;      //   160,000
    float* h_out = (float*)d_out;
    float* e_out = (float*)d_out + 2560000;

    // CSR arrays alias Q's region (Q is dead after score_kernel).
    int* hist   = (int*)d_ws;          // 20,000
    int* offs   = (int*)d_ws + 20000;  // 20,001
    int* cursor = (int*)d_ws + 40001;  // 20,000
    int* eid    = (int*)d_ws + 60001;  // 640,000

    qkv_gemm<<<dim3(313, 6), 256, 0, stream>>>(h, Wq, bq, Wk, bk, Wv, bv, Q, K, V);
    score_kernel<<<20000, 256, 0, stream>>>(Q, K, src, dst, adj2, rel, score);
    gedge_a<<<1250, 256, 0, stream>>>(e, emap, Wpe, bpe, Wap, bap, score, e_out);
    exp_kernel<<<5000, 256, 0, stream>>>(score);
    eout_gemm<<<5000, 256, 0, stream>>>(e_out, Woute, boute);

    hipMemsetAsync(hist, 0, 20000 * sizeof(int), stream);
    hist_kernel<<<2500, 256, 0, stream>>>(dst, hist);
    scan_kernel<<<1, 256, 0, stream>>>(hist, offs, cursor);
    scatter_kernel<<<2500, 256, 0, stream>>>(dst, cursor, eid);
    csr_aggregate<<<5000, 256, 0, stream>>>(V, src, score, offs, eid, wV, z);

    hout_gemm<<<dim3(313, 2), 256, 0, stream>>>(wV, z, Wout, bout, h_out);
}

// Round 5
// 442.295 us; speedup vs baseline: 1.5957x; 1.0152x over previous
//
#include <hip/hip_runtime.h>
#include <hip/hip_bf16.h>

#define NN 20000
#define EF 640000
#define EG 160000

typedef __attribute__((ext_vector_type(8))) short bf16x8;
typedef __attribute__((ext_vector_type(4))) float f32x4;

__device__ inline short f2bf(float f) {
    union { float f; unsigned u; } x; x.f = f;
    unsigned r = x.u + 0x7FFF + ((x.u >> 16) & 1);   // RNE
    return (short)(r >> 16);
}

// ---------------------------------------------------------------------------
// Weight transpose+convert: BT[n][k] = W[k][n] as bf16. 5 matrices via grid.y.
// ---------------------------------------------------------------------------
__global__ __launch_bounds__(256) void wconv_kernel(
    const float* __restrict__ W0, const float* __restrict__ W1,
    const float* __restrict__ W2, const float* __restrict__ W3,
    const float* __restrict__ W4, short* __restrict__ B0,
    short* __restrict__ B1, short* __restrict__ B2,
    short* __restrict__ B3, short* __restrict__ B4)
{
    const float* W; short* B;
    switch (blockIdx.y) {
        case 0: W = W0; B = B0; break;
        case 1: W = W1; B = B1; break;
        case 2: W = W2; B = B2; break;
        case 3: W = W3; B = B3; break;
        default: W = W4; B = B4; break;
    }
    int i = blockIdx.x * 256 + threadIdx.x;   // 0..4095
    int n = i >> 5;
    int k0 = (i & 31) * 4;
    #pragma unroll
    for (int j = 0; j < 4; ++j)
        B[n * 128 + k0 + j] = f2bf(W[(k0 + j) * 128 + n]);
}

// ---------------------------------------------------------------------------
// Generic MFMA GEMM, N=128, K=128: out[M][128] = A[M][128] @ BT^T + bias.
// BT is bf16 [128n][128k] (pre-transposed). A is f32 (cvt in-reg) or bf16.
// 4 waves/block, wave owns 32 rows; no LDS, no barriers. In-place safe
// (block-row ownership; all A loads precede stores).
// ---------------------------------------------------------------------------
template <bool AF32>
__global__ __launch_bounds__(256) void mfma_gemm_n128(
    const void* __restrict__ Ap, const short* __restrict__ BT,
    const float* __restrict__ bias, float* __restrict__ out, int M)
{
    int lane = threadIdx.x & 63;
    int w = threadIdx.x >> 6;
    int row0 = blockIdx.x * 128 + w * 32;
    int l15 = lane & 15, lhi = lane >> 4;

    bf16x8 a[2][4];
    #pragma unroll
    for (int m = 0; m < 2; ++m) {
        int r = row0 + m * 16 + l15;
        bool ok = r < M;
        #pragma unroll
        for (int ks = 0; ks < 4; ++ks) {
            int k0 = ks * 32 + lhi * 8;
            if (AF32) {
                if (ok) {
                    const float* ap = (const float*)Ap + (size_t)r * 128 + k0;
                    float4 f0 = *(const float4*)ap;
                    float4 f1 = *(const float4*)(ap + 4);
                    a[m][ks][0] = f2bf(f0.x); a[m][ks][1] = f2bf(f0.y);
                    a[m][ks][2] = f2bf(f0.z); a[m][ks][3] = f2bf(f0.w);
                    a[m][ks][4] = f2bf(f1.x); a[m][ks][5] = f2bf(f1.y);
                    a[m][ks][6] = f2bf(f1.z); a[m][ks][7] = f2bf(f1.w);
                } else {
                    #pragma unroll
                    for (int j = 0; j < 8; ++j) a[m][ks][j] = 0;
                }
            } else {
                if (ok)
                    a[m][ks] = *(const bf16x8*)((const short*)Ap + (size_t)r * 128 + k0);
                else {
                    #pragma unroll
                    for (int j = 0; j < 8; ++j) a[m][ks][j] = 0;
                }
            }
        }
    }

    f32x4 acc[2][8];
    #pragma unroll
    for (int m = 0; m < 2; ++m)
        #pragma unroll
        for (int n = 0; n < 8; ++n) {
            acc[m][n][0] = 0.f; acc[m][n][1] = 0.f;
            acc[m][n][2] = 0.f; acc[m][n][3] = 0.f;
        }

    #pragma unroll
    for (int n = 0; n < 8; ++n) {
        #pragma unroll
        for (int ks = 0; ks < 4; ++ks) {
            bf16x8 b = *(const bf16x8*)(BT + (size_t)(n * 16 + l15) * 128 + ks * 32 + lhi * 8);
            acc[0][n] = __builtin_amdgcn_mfma_f32_16x16x32_bf16(a[0][ks], b, acc[0][n], 0, 0, 0);
            acc[1][n] = __builtin_amdgcn_mfma_f32_16x16x32_bf16(a[1][ks], b, acc[1][n], 0, 0, 0);
        }
    }

    #pragma unroll
    for (int m = 0; m < 2; ++m) {
        #pragma unroll
        for (int n = 0; n < 8; ++n) {
            int col = n * 16 + l15;
            float bs = bias[col];
            #pragma unroll
            for (int r4 = 0; r4 < 4; ++r4) {
                int row = row0 + m * 16 + lhi * 4 + r4;
                if (row < M) out[(size_t)row * 128 + col] = acc[m][n][r4] + bs;
            }
        }
    }
}

// ---------------------------------------------------------------------------
// score1 for all full-graph edges: 8 lanes per edge (one per head)
// ---------------------------------------------------------------------------
__global__ __launch_bounds__(256) void score_kernel(
    const float* __restrict__ Q, const float* __restrict__ K,
    const int* __restrict__ src, const int* __restrict__ dst,
    const float* __restrict__ adj2, const float* __restrict__ rel,
    float* __restrict__ score)
{
    int tid = blockIdx.x * 256 + threadIdx.x;   // over EF*8
    if (tid >= EF * 8) return;
    int e = tid >> 3, hh = tid & 7;
    int s = src[e], d = dst[e];
    const float4* Kp = (const float4*)(K + (size_t)s * 128 + hh * 16);
    const float4* Qp = (const float4*)(Q + (size_t)d * 128 + hh * 16);
    float dot = 0.f;
    #pragma unroll
    for (int j = 0; j < 4; ++j) {
        float4 a = Kp[j]; float4 b = Qp[j];
        dot += a.x * b.x + a.y * b.y + a.z * b.z + a.w * b.w;
    }
    dot *= 0.25f;
    float sc = __expf(fminf(fmaxf(dot, -5.f), 5.f) * adj2[e]) + rel[e];
    score[tid] = sc;
}

// ---------------------------------------------------------------------------
// g-edge pipeline (one wave per g-edge). Weights hoisted to registers.
// ---------------------------------------------------------------------------
__global__ __launch_bounds__(256) void gedge_a(
    const float* __restrict__ efeat, const int* __restrict__ emap,
    const float* __restrict__ Wpe, const float* __restrict__ bpe,
    const float* __restrict__ Wap, const float* __restrict__ bap,
    float* __restrict__ score, float* __restrict__ tmp)
{
    int lane = threadIdx.x & 63;
    int wid = (blockIdx.x << 2) | (threadIdx.x >> 6);
    int nw = gridDim.x << 2;

    float wpe0[8], wpe1[8], wap0[8], wap1[8];
    #pragma unroll
    for (int hh = 0; hh < 8; ++hh) {
        wpe0[hh] = Wpe[(2 * lane) * 8 + hh];
        wpe1[hh] = Wpe[(2 * lane + 1) * 8 + hh];
        wap0[hh] = Wap[hh * 128 + 2 * lane];
        wap1[hh] = Wap[hh * 128 + 2 * lane + 1];
    }
    float bap0 = bap[2 * lane], bap1 = bap[2 * lane + 1];
    float bpe_l = bpe[lane & 7];

    const int b2 = (lane >> 5) & 1;
    const int b1 = (lane >> 4) & 1;
    const int b0 = (lane >> 3) & 1;

    for (int i = wid; i < EG; i += nw) {
        int fidx = __builtin_amdgcn_readfirstlane(emap[i]);
        float gs[8];
        #pragma unroll
        for (int hh = 0; hh < 8; ++hh) gs[hh] = score[fidx * 8 + hh];
        float2 ev = ((const float2*)efeat)[(size_t)i * 64 + lane];

        float p[8];
        #pragma unroll
        for (int hh = 0; hh < 8; ++hh)
            p[hh] = ev.x * wpe0[hh] + ev.y * wpe1[hh];

        float q[4];
        #pragma unroll
        for (int j = 0; j < 4; ++j) {
            float send = b2 ? p[j] : p[4 + j];
            float recv = __shfl_xor(send, 32);
            q[j] = (b2 ? p[4 + j] : p[j]) + recv;
        }
        float r2[2];
        #pragma unroll
        for (int j = 0; j < 2; ++j) {
            float send = b1 ? q[j] : q[2 + j];
            float recv = __shfl_xor(send, 16);
            r2[j] = (b1 ? q[2 + j] : q[j]) + recv;
        }
        {
            float send = b0 ? r2[0] : r2[1];
            float recv = __shfl_xor(send, 8);
            r2[0] = (b0 ? r2[1] : r2[0]) + recv;
        }
        float s = r2[0];
        s += __shfl_xor(s, 4);
        s += __shfl_xor(s, 2);
        s += __shfl_xor(s, 1);
        float ph = __shfl(s, (lane & 7) * 8);

        float gv = gs[0];
        #pragma unroll
        for (int hh = 1; hh < 8; ++hh) gv = (lane == hh) ? gs[hh] : gv;
        if (lane < 8)
            score[fidx * 8 + lane] = fminf(fmaxf(gv, -5.f), 5.f) + bpe_l + ph;

        float ap0 = bap0, ap1 = bap1;
        #pragma unroll
        for (int hh = 0; hh < 8; ++hh) {
            ap0 += gs[hh] * wap0[hh];
            ap1 += gs[hh] * wap1[hh];
        }
        ((float2*)tmp)[(size_t)i * 64 + lane] = make_float2(ap0 + ev.x, ap1 + ev.y);
    }
}

// ---------------------------------------------------------------------------
// in-place exp(clip(score)), float4-vectorized
// ---------------------------------------------------------------------------
__global__ __launch_bounds__(256) void exp_kernel(float* __restrict__ score)
{
    int i = blockIdx.x * 256 + threadIdx.x;
    if (i >= EF * 2) return;
    float4 v = ((float4*)score)[i];
    v.x = __expf(fminf(fmaxf(v.x, -5.f), 5.f));
    v.y = __expf(fminf(fmaxf(v.y, -5.f), 5.f));
    v.z = __expf(fminf(fmaxf(v.z, -5.f), 5.f));
    v.w = __expf(fminf(fmaxf(v.w, -5.f), 5.f));
    ((float4*)score)[i] = v;
}

// ---------------------------------------------------------------------------
// CSR build
// ---------------------------------------------------------------------------
__global__ __launch_bounds__(256) void hist_kernel(
    const int* __restrict__ dst, int* __restrict__ hist)
{
    int i = blockIdx.x * 256 + threadIdx.x;
    if (i < EF) atomicAdd(&hist[dst[i]], 1);
}

__global__ __launch_bounds__(256) void scan_kernel(
    const int* __restrict__ hist, int* __restrict__ offs,
    int* __restrict__ cursor)
{
    __shared__ int sums[256];
    int tid = threadIdx.x;
    const int CH = 80;
    int base = tid * CH;
    int local = 0;
    for (int i = 0; i < CH; ++i) {
        int idx = base + i;
        if (idx < NN) local += hist[idx];
    }
    sums[tid] = local;
    __syncthreads();
    for (int s = 1; s < 256; s <<= 1) {
        int v = (tid >= s) ? sums[tid - s] : 0;
        __syncthreads();
        sums[tid] += v;
        __syncthreads();
    }
    int run = sums[tid] - local;
    for (int i = 0; i < CH; ++i) {
        int idx = base + i;
        if (idx < NN) {
            offs[idx] = run;
            cursor[idx] = run;
            run += hist[idx];
        }
    }
    if (tid == 255) offs[NN] = EF;
}

__global__ __launch_bounds__(256) void scatter_kernel(
    const int* __restrict__ dst, int* __restrict__ cursor,
    int* __restrict__ eid)
{
    int i = blockIdx.x * 256 + threadIdx.x;
    if (i < EF) {
        int p = atomicAdd(&cursor[dst[i]], 1);
        eid[p] = i;
    }
}

// ---------------------------------------------------------------------------
// CSR aggregation: wave per node; writes NORMALIZED bf16 wV row directly.
// ---------------------------------------------------------------------------
__global__ __launch_bounds__(256) void csr_aggregate(
    const float* __restrict__ V, const int* __restrict__ srcArr,
    const float* __restrict__ score, const int* __restrict__ offs,
    const int* __restrict__ eid, unsigned* __restrict__ wVn)
{
    int lane = threadIdx.x & 63;
    int wid = (blockIdx.x << 2) | (threadIdx.x >> 6);
    if (wid >= NN) return;
    int beg = offs[wid], end = offs[wid + 1];
    int hh = lane >> 3;

    float accx = 0.f, accy = 0.f, zacc = 0.f;
    int p = beg;
    for (; p + 4 <= end; p += 4) {
        int e0 = eid[p],     e1 = eid[p + 1];
        int e2 = eid[p + 2], e3 = eid[p + 3];
        int s0 = srcArr[e0], s1 = srcArr[e1];
        int s2 = srcArr[e2], s3 = srcArr[e3];
        float sc0 = score[e0 * 8 + hh];
        float sc1 = score[e1 * 8 + hh];
        float sc2 = score[e2 * 8 + hh];
        float sc3 = score[e3 * 8 + hh];
        float2 v0 = *(const float2*)(V + (size_t)s0 * 128 + lane * 2);
        float2 v1 = *(const float2*)(V + (size_t)s1 * 128 + lane * 2);
        float2 v2 = *(const float2*)(V + (size_t)s2 * 128 + lane * 2);
        float2 v3 = *(const float2*)(V + (size_t)s3 * 128 + lane * 2);
        accx += v0.x * sc0; accy += v0.y * sc0;
        accx += v1.x * sc1; accy += v1.y * sc1;
        accx += v2.x * sc2; accy += v2.y * sc2;
        accx += v3.x * sc3; accy += v3.y * sc3;
        zacc += (sc0 + sc1) + (sc2 + sc3);
    }
    for (; p < end; ++p) {
        int e = eid[p];
        int s = srcArr[e];
        float sc = score[e * 8 + hh];
        float2 v = *(const float2*)(V + (size_t)s * 128 + lane * 2);
        accx += v.x * sc; accy += v.y * sc;
        zacc += sc;
    }
    float rz = 1.f / (zacc + 1e-6f);
    unsigned lo = (unsigned short)f2bf(accx * rz);
    unsigned hi = (unsigned short)f2bf(accy * rz);
    wVn[(size_t)wid * 64 + lane] = lo | (hi << 16);
}

extern "C" void kernel_launch(void* const* d_in, const int* in_sizes, int n_in,
                              void* d_out, int out_size, void* d_ws, size_t ws_size,
                              hipStream_t stream)
{
    const float* h    = (const float*)d_in[0];
    const float* e    = (const float*)d_in[1];
    const float* adj2 = (const float*)d_in[2];
    const float* rel  = (const float*)d_in[3];
    const int*   src  = (const int*)d_in[4];
    const int*   dst  = (const int*)d_in[5];
    const int*   emap = (const int*)d_in[6];
    const float* Wq = (const float*)d_in[7];   const float* bq = (const float*)d_in[8];
    const float* Wk = (const float*)d_in[9];   const float* bk = (const float*)d_in[10];
    const float* Wv = (const float*)d_in[11];  const float* bv = (const float*)d_in[12];
    const float* Wpe = (const float*)d_in[13]; const float* bpe = (const float*)d_in[14];
    const float* Wap = (const float*)d_in[15]; const float* bap = (const float*)d_in[16];
    const float* Wout = (const float*)d_in[17]; const float* bout = (const float*)d_in[18];
    const float* Woute = (const float*)d_in[19]; const float* boute = (const float*)d_in[20];

    float* ws    = (float*)d_ws;
    float* Q     = ws;                  // 2,560,000 f32 (CSR arrays alias later)
    float* K     = ws + 2560000;
    float* V     = ws + 5120000;
    float* score = ws + 7680000;        // 5,120,000 f32
    unsigned* wVn = (unsigned*)(ws + 12800000);   // 20000*64 u32 (bf16x2)
    // bf16 transposed weights in the old z region:
    short* WqT    = (short*)(ws + 15360000);      // 16384 bf16 each
    short* WkT    = (short*)(ws + 15368192);
    short* WvT    = (short*)(ws + 15376384);
    short* WoutT  = (short*)(ws + 15384576);
    short* WouteT = (short*)(ws + 15392768);
    float* h_out = (float*)d_out;
    float* e_out = (float*)d_out + 2560000;       // also tmp for gedge_a

    int* hist   = (int*)d_ws;           // alias Q region (dead after score)
    int* offs   = (int*)d_ws + 20000;
    int* cursor = (int*)d_ws + 40001;
    int* eid    = (int*)d_ws + 60001;

    wconv_kernel<<<dim3(16, 5), 256, 0, stream>>>(
        Wq, Wk, Wv, Wout, Woute, WqT, WkT, WvT, WoutT, WouteT);

    mfma_gemm_n128<true><<<157, 256, 0, stream>>>(h, WqT, bq, Q, NN);
    mfma_gemm_n128<true><<<157, 256, 0, stream>>>(h, WkT, bk, K, NN);
    mfma_gemm_n128<true><<<157, 256, 0, stream>>>(h, WvT, bv, V, NN);

    score_kernel<<<20000, 256, 0, stream>>>(Q, K, src, dst, adj2, rel, score);
    gedge_a<<<1250, 256, 0, stream>>>(e, emap, Wpe, bpe, Wap, bap, score, e_out);
    exp_kernel<<<5000, 256, 0, stream>>>(score);

    // e_out = tmp @ Woute + boute, in place (block-row ownership)
    mfma_gemm_n128<true><<<1250, 256, 0, stream>>>(e_out, WouteT, boute, e_out, EG);

    hipMemsetAsync(hist, 0, 20000 * sizeof(int), stream);
    hist_kernel<<<2500, 256, 0, stream>>>(dst, hist);
    scan_kernel<<<1, 256, 0, stream>>>(hist, offs, cursor);
    scatter_kernel<<<2500, 256, 0, stream>>>(dst, cursor, eid);
    csr_aggregate<<<5000, 256, 0, stream>>>(V, src, score, offs, eid, wVn);

    mfma_gemm_n128<false><<<157, 256, 0, stream>>>(wVn, WoutT, bout, h_out, NN);
}

// Round 6
// 362.927 us; speedup vs baseline: 1.9446x; 1.2187x over previous
//
#include <hip/hip_runtime.h>
#include <hip/hip_bf16.h>

#define NN 20000
#define EF 640000
#define EG 160000

typedef __attribute__((ext_vector_type(8))) short bf16x8;
typedef __attribute__((ext_vector_type(4))) float f32x4;

__device__ inline short f2bf(float f) {
    union { float f; unsigned u; } x; x.f = f;
    unsigned r = x.u + 0x7FFF + ((x.u >> 16) & 1);   // RNE
    return (short)(r >> 16);
}
__device__ inline float bf2f(short s) {
    union { float f; unsigned u; } x;
    x.u = ((unsigned)(unsigned short)s) << 16;
    return x.f;
}

// ---------------------------------------------------------------------------
// Weight transpose+convert: BT[n][k] = W[k][n] as bf16. 5 matrices via grid.y.
// ---------------------------------------------------------------------------
__global__ __launch_bounds__(256) void wconv_kernel(
    const float* __restrict__ W0, const float* __restrict__ W1,
    const float* __restrict__ W2, const float* __restrict__ W3,
    const float* __restrict__ W4, short* __restrict__ B0,
    short* __restrict__ B1, short* __restrict__ B2,
    short* __restrict__ B3, short* __restrict__ B4)
{
    const float* W; short* B;
    switch (blockIdx.y) {
        case 0: W = W0; B = B0; break;
        case 1: W = W1; B = B1; break;
        case 2: W = W2; B = B2; break;
        case 3: W = W3; B = B3; break;
        default: W = W4; B = B4; break;
    }
    int i = blockIdx.x * 256 + threadIdx.x;   // 0..4095
    int n = i >> 5;
    int k0 = (i & 31) * 4;
    #pragma unroll
    for (int j = 0; j < 4; ++j)
        B[n * 128 + k0 + j] = f2bf(W[(k0 + j) * 128 + n]);
}

// WpeT16[n][k]: n<8 -> Wpe[k][n], else 0 (pad to N=16)
__global__ __launch_bounds__(256) void wpe_kernel(
    const float* __restrict__ Wpe, short* __restrict__ WpeT16)
{
    int i = blockIdx.x * 256 + threadIdx.x;   // 0..2047
    int n = i >> 7, k = i & 127;
    WpeT16[n * 128 + k] = (n < 8) ? f2bf(Wpe[k * 8 + n]) : 0;
}

// Wcomb = Wap@Woute -> WcombP[j][kk] (kk<8; pad to 32), bcomb = bap@Woute+boute
__global__ __launch_bounds__(128) void wcomb_kernel(
    const float* __restrict__ Wap, const float* __restrict__ bap,
    const float* __restrict__ Woute, const float* __restrict__ boute,
    short* __restrict__ WcombP, float* __restrict__ bcomb)
{
    int j = threadIdx.x;   // 0..127
    float bc = boute[j];
    for (int k = 0; k < 128; ++k) bc += bap[k] * Woute[k * 128 + j];
    bcomb[j] = bc;
    #pragma unroll
    for (int i = 0; i < 8; ++i) {
        float s = 0.f;
        for (int k = 0; k < 128; ++k) s += Wap[i * 128 + k] * Woute[k * 128 + j];
        WcombP[j * 32 + i] = f2bf(s);
    }
    #pragma unroll
    for (int i = 8; i < 32; ++i) WcombP[j * 32 + i] = 0;
}

// ---------------------------------------------------------------------------
// MFMA GEMM N=128,K=128, f32 A (cvt in-reg), bf16 OUT (for Q/K/V).
// ---------------------------------------------------------------------------
__global__ __launch_bounds__(256) void mfma_gemm_obf16(
    const float* __restrict__ Ap, const short* __restrict__ BT,
    const float* __restrict__ bias, short* __restrict__ out, int M)
{
    int lane = threadIdx.x & 63;
    int w = threadIdx.x >> 6;
    int row0 = blockIdx.x * 128 + w * 32;
    int l15 = lane & 15, lhi = lane >> 4;

    bf16x8 a[2][4];
    #pragma unroll
    for (int m = 0; m < 2; ++m) {
        int r = row0 + m * 16 + l15;
        bool ok = r < M;
        #pragma unroll
        for (int ks = 0; ks < 4; ++ks) {
            if (ok) {
                const float* ap = Ap + (size_t)r * 128 + ks * 32 + lhi * 8;
                float4 f0 = *(const float4*)ap;
                float4 f1 = *(const float4*)(ap + 4);
                a[m][ks][0] = f2bf(f0.x); a[m][ks][1] = f2bf(f0.y);
                a[m][ks][2] = f2bf(f0.z); a[m][ks][3] = f2bf(f0.w);
                a[m][ks][4] = f2bf(f1.x); a[m][ks][5] = f2bf(f1.y);
                a[m][ks][6] = f2bf(f1.z); a[m][ks][7] = f2bf(f1.w);
            } else {
                #pragma unroll
                for (int j = 0; j < 8; ++j) a[m][ks][j] = 0;
            }
        }
    }
    f32x4 acc[2][8];
    #pragma unroll
    for (int m = 0; m < 2; ++m)
        #pragma unroll
        for (int n = 0; n < 8; ++n)
            acc[m][n] = (f32x4){0.f, 0.f, 0.f, 0.f};

    #pragma unroll
    for (int n = 0; n < 8; ++n)
        #pragma unroll
        for (int ks = 0; ks < 4; ++ks) {
            bf16x8 b = *(const bf16x8*)(BT + (size_t)(n * 16 + l15) * 128 + ks * 32 + lhi * 8);
            acc[0][n] = __builtin_amdgcn_mfma_f32_16x16x32_bf16(a[0][ks], b, acc[0][n], 0, 0, 0);
            acc[1][n] = __builtin_amdgcn_mfma_f32_16x16x32_bf16(a[1][ks], b, acc[1][n], 0, 0, 0);
        }

    #pragma unroll
    for (int m = 0; m < 2; ++m)
        #pragma unroll
        for (int n = 0; n < 8; ++n) {
            int col = n * 16 + l15;
            float bs = bias[col];
            #pragma unroll
            for (int r4 = 0; r4 < 4; ++r4) {
                int row = row0 + m * 16 + lhi * 4 + r4;
                if (row < M) out[(size_t)row * 128 + col] = f2bf(acc[m][n][r4] + bs);
            }
        }
}

// ---------------------------------------------------------------------------
// MFMA GEMM N=128,K=128, bf16 A, f32 OUT (for h_out from wVn).
// ---------------------------------------------------------------------------
__global__ __launch_bounds__(256) void mfma_gemm_abf16(
    const short* __restrict__ Ap, const short* __restrict__ BT,
    const float* __restrict__ bias, float* __restrict__ out, int M)
{
    int lane = threadIdx.x & 63;
    int w = threadIdx.x >> 6;
    int row0 = blockIdx.x * 128 + w * 32;
    int l15 = lane & 15, lhi = lane >> 4;

    bf16x8 a[2][4];
    #pragma unroll
    for (int m = 0; m < 2; ++m) {
        int r = row0 + m * 16 + l15;
        bool ok = r < M;
        #pragma unroll
        for (int ks = 0; ks < 4; ++ks) {
            if (ok) a[m][ks] = *(const bf16x8*)(Ap + (size_t)r * 128 + ks * 32 + lhi * 8);
            else {
                #pragma unroll
                for (int j = 0; j < 8; ++j) a[m][ks][j] = 0;
            }
        }
    }
    f32x4 acc[2][8];
    #pragma unroll
    for (int m = 0; m < 2; ++m)
        #pragma unroll
        for (int n = 0; n < 8; ++n)
            acc[m][n] = (f32x4){0.f, 0.f, 0.f, 0.f};

    #pragma unroll
    for (int n = 0; n < 8; ++n)
        #pragma unroll
        for (int ks = 0; ks < 4; ++ks) {
            bf16x8 b = *(const bf16x8*)(BT + (size_t)(n * 16 + l15) * 128 + ks * 32 + lhi * 8);
            acc[0][n] = __builtin_amdgcn_mfma_f32_16x16x32_bf16(a[0][ks], b, acc[0][n], 0, 0, 0);
            acc[1][n] = __builtin_amdgcn_mfma_f32_16x16x32_bf16(a[1][ks], b, acc[1][n], 0, 0, 0);
        }

    #pragma unroll
    for (int m = 0; m < 2; ++m)
        #pragma unroll
        for (int n = 0; n < 8; ++n) {
            int col = n * 16 + l15;
            float bs = bias[col];
            #pragma unroll
            for (int r4 = 0; r4 < 4; ++r4) {
                int row = row0 + m * 16 + lhi * 4 + r4;
                if (row < M) out[(size_t)row * 128 + col] = acc[m][n][r4] + bs;
            }
        }
}

// ---------------------------------------------------------------------------
// pe = e @ Wpe + bpe  (MFMA, N=16 padded, only cols 0..7 written)
// ---------------------------------------------------------------------------
__global__ __launch_bounds__(256) void mfma_pe(
    const float* __restrict__ Ap, const short* __restrict__ WpeT16,
    const float* __restrict__ bpe, float* __restrict__ pe)
{
    int lane = threadIdx.x & 63;
    int w = threadIdx.x >> 6;
    int row0 = blockIdx.x * 128 + w * 32;
    int l15 = lane & 15, lhi = lane >> 4;

    bf16x8 a[2][4];
    #pragma unroll
    for (int m = 0; m < 2; ++m) {
        int r = row0 + m * 16 + l15;
        #pragma unroll
        for (int ks = 0; ks < 4; ++ks) {
            const float* ap = Ap + (size_t)r * 128 + ks * 32 + lhi * 8;
            float4 f0 = *(const float4*)ap;
            float4 f1 = *(const float4*)(ap + 4);
            a[m][ks][0] = f2bf(f0.x); a[m][ks][1] = f2bf(f0.y);
            a[m][ks][2] = f2bf(f0.z); a[m][ks][3] = f2bf(f0.w);
            a[m][ks][4] = f2bf(f1.x); a[m][ks][5] = f2bf(f1.y);
            a[m][ks][6] = f2bf(f1.z); a[m][ks][7] = f2bf(f1.w);
        }
    }
    f32x4 acc[2];
    acc[0] = (f32x4){0.f, 0.f, 0.f, 0.f};
    acc[1] = (f32x4){0.f, 0.f, 0.f, 0.f};
    #pragma unroll
    for (int ks = 0; ks < 4; ++ks) {
        bf16x8 b = *(const bf16x8*)(WpeT16 + (size_t)l15 * 128 + ks * 32 + lhi * 8);
        acc[0] = __builtin_amdgcn_mfma_f32_16x16x32_bf16(a[0][ks], b, acc[0], 0, 0, 0);
        acc[1] = __builtin_amdgcn_mfma_f32_16x16x32_bf16(a[1][ks], b, acc[1], 0, 0, 0);
    }
    if (l15 < 8) {
        float bs = bpe[l15];
        #pragma unroll
        for (int m = 0; m < 2; ++m)
            #pragma unroll
            for (int r4 = 0; r4 < 4; ++r4) {
                int row = row0 + m * 16 + lhi * 4 + r4;
                pe[(size_t)row * 8 + l15] = acc[m][r4] + bs;
            }
    }
}

// ---------------------------------------------------------------------------
// update: gsb = bf16(score1[emap]); score[emap] = clip(score1) + pe
// ---------------------------------------------------------------------------
__global__ __launch_bounds__(256) void update_kernel(
    const int* __restrict__ emap, const float* __restrict__ pe,
    float* __restrict__ score, short* __restrict__ gsb)
{
    int idx = blockIdx.x * 256 + threadIdx.x;   // over EG*8
    if (idx >= EG * 8) return;
    int i = idx >> 3, hh = idx & 7;
    int fidx = emap[i];
    float gs = score[fidx * 8 + hh];
    gsb[idx] = f2bf(gs);
    score[fidx * 8 + hh] = fminf(fmaxf(gs, -5.f), 5.f) + pe[idx];
}

// ---------------------------------------------------------------------------
// e_out = e @ Woute + gs @ Wcomb + bcomb   (fused, MFMA, f32 out)
// ---------------------------------------------------------------------------
__global__ __launch_bounds__(256) void mfma_eout(
    const float* __restrict__ Ap, const short* __restrict__ WouteT,
    const short* __restrict__ WcombP, const float* __restrict__ bcomb,
    const short* __restrict__ gsb, float* __restrict__ out)
{
    int lane = threadIdx.x & 63;
    int w = threadIdx.x >> 6;
    int row0 = blockIdx.x * 128 + w * 32;
    int l15 = lane & 15, lhi = lane >> 4;

    bf16x8 a[2][4], ag[2];
    #pragma unroll
    for (int m = 0; m < 2; ++m) {
        int r = row0 + m * 16 + l15;
        #pragma unroll
        for (int ks = 0; ks < 4; ++ks) {
            const float* ap = Ap + (size_t)r * 128 + ks * 32 + lhi * 8;
            float4 f0 = *(const float4*)ap;
            float4 f1 = *(const float4*)(ap + 4);
            a[m][ks][0] = f2bf(f0.x); a[m][ks][1] = f2bf(f0.y);
            a[m][ks][2] = f2bf(f0.z); a[m][ks][3] = f2bf(f0.w);
            a[m][ks][4] = f2bf(f1.x); a[m][ks][5] = f2bf(f1.y);
            a[m][ks][6] = f2bf(f1.z); a[m][ks][7] = f2bf(f1.w);
        }
        if (lhi == 0) ag[m] = *(const bf16x8*)(gsb + (size_t)r * 8);
        else {
            #pragma unroll
            for (int j = 0; j < 8; ++j) ag[m][j] = 0;
        }
    }
    f32x4 acc[2][8];
    #pragma unroll
    for (int m = 0; m < 2; ++m)
        #pragma unroll
        for (int n = 0; n < 8; ++n)
            acc[m][n] = (f32x4){0.f, 0.f, 0.f, 0.f};

    #pragma unroll
    for (int n = 0; n < 8; ++n) {
        #pragma unroll
        for (int ks = 0; ks < 4; ++ks) {
            bf16x8 b = *(const bf16x8*)(WouteT + (size_t)(n * 16 + l15) * 128 + ks * 32 + lhi * 8);
            acc[0][n] = __builtin_amdgcn_mfma_f32_16x16x32_bf16(a[0][ks], b, acc[0][n], 0, 0, 0);
            acc[1][n] = __builtin_amdgcn_mfma_f32_16x16x32_bf16(a[1][ks], b, acc[1][n], 0, 0, 0);
        }
        bf16x8 bg = *(const bf16x8*)(WcombP + (size_t)(n * 16 + l15) * 32 + lhi * 8);
        acc[0][n] = __builtin_amdgcn_mfma_f32_16x16x32_bf16(ag[0], bg, acc[0][n], 0, 0, 0);
        acc[1][n] = __builtin_amdgcn_mfma_f32_16x16x32_bf16(ag[1], bg, acc[1][n], 0, 0, 0);
    }

    #pragma unroll
    for (int m = 0; m < 2; ++m)
        #pragma unroll
        for (int n = 0; n < 8; ++n) {
            int col = n * 16 + l15;
            float bs = bcomb[col];
            #pragma unroll
            for (int r4 = 0; r4 < 4; ++r4) {
                int row = row0 + m * 16 + lhi * 4 + r4;
                out[(size_t)row * 128 + col] = acc[m][n][r4] + bs;
            }
        }
}

// ---------------------------------------------------------------------------
// score1 for all full-graph edges: 8 lanes per edge, bf16 Q/K gathers
// ---------------------------------------------------------------------------
__global__ __launch_bounds__(256) void score_kernel(
    const short* __restrict__ Qb, const short* __restrict__ Kb,
    const int* __restrict__ src, const int* __restrict__ dst,
    const float* __restrict__ adj2, const float* __restrict__ rel,
    float* __restrict__ score)
{
    int tid = blockIdx.x * 256 + threadIdx.x;   // over EF*8
    if (tid >= EF * 8) return;
    int e = tid >> 3, hh = tid & 7;
    int s = src[e], d = dst[e];
    const bf16x8* Kp = (const bf16x8*)(Kb + (size_t)s * 128 + hh * 16);
    const bf16x8* Qp = (const bf16x8*)(Qb + (size_t)d * 128 + hh * 16);
    bf16x8 k0 = Kp[0], k1 = Kp[1];
    bf16x8 q0 = Qp[0], q1 = Qp[1];
    float dot = 0.f;
    #pragma unroll
    for (int j = 0; j < 8; ++j) dot += bf2f(k0[j]) * bf2f(q0[j]);
    #pragma unroll
    for (int j = 0; j < 8; ++j) dot += bf2f(k1[j]) * bf2f(q1[j]);
    dot *= 0.25f;
    float sc = __expf(fminf(fmaxf(dot, -5.f), 5.f) * adj2[e]) + rel[e];
    score[tid] = sc;
}

// ---------------------------------------------------------------------------
// CSR build
// ---------------------------------------------------------------------------
__global__ __launch_bounds__(256) void hist_kernel(
    const int* __restrict__ dst, int* __restrict__ hist)
{
    int i = blockIdx.x * 256 + threadIdx.x;
    if (i < EF) atomicAdd(&hist[dst[i]], 1);
}

__global__ __launch_bounds__(256) void scan_kernel(
    const int* __restrict__ hist, int* __restrict__ offs,
    int* __restrict__ cursor)
{
    __shared__ int sums[256];
    int tid = threadIdx.x;
    const int CH = 80;
    int base = tid * CH;
    int local = 0;
    for (int i = 0; i < CH; ++i) {
        int idx = base + i;
        if (idx < NN) local += hist[idx];
    }
    sums[tid] = local;
    __syncthreads();
    for (int s = 1; s < 256; s <<= 1) {
        int v = (tid >= s) ? sums[tid - s] : 0;
        __syncthreads();
        sums[tid] += v;
        __syncthreads();
    }
    int run = sums[tid] - local;
    for (int i = 0; i < CH; ++i) {
        int idx = base + i;
        if (idx < NN) {
            offs[idx] = run;
            cursor[idx] = run;
            run += hist[idx];
        }
    }
    if (tid == 255) offs[NN] = EF;
}

__global__ __launch_bounds__(256) void scatter_kernel(
    const int* __restrict__ dst, int* __restrict__ cursor,
    int* __restrict__ eid)
{
    int i = blockIdx.x * 256 + threadIdx.x;
    if (i < EF) {
        int p = atomicAdd(&cursor[dst[i]], 1);
        eid[p] = i;
    }
}

// ---------------------------------------------------------------------------
// CSR aggregation: wave per node; exp folded in; bf16 V; normalized bf16 out.
// ---------------------------------------------------------------------------
__global__ __launch_bounds__(256) void csr_aggregate(
    const unsigned* __restrict__ Vb2, const int* __restrict__ srcArr,
    const float* __restrict__ score, const int* __restrict__ offs,
    const int* __restrict__ eid, unsigned* __restrict__ wVn)
{
    int lane = threadIdx.x & 63;
    int wid = (blockIdx.x << 2) | (threadIdx.x >> 6);
    if (wid >= NN) return;
    int beg = offs[wid], end = offs[wid + 1];
    int hh = lane >> 3;

    float accx = 0.f, accy = 0.f, zacc = 0.f;
    int p = beg;
    for (; p + 4 <= end; p += 4) {
        int e0 = eid[p],     e1 = eid[p + 1];
        int e2 = eid[p + 2], e3 = eid[p + 3];
        int s0 = srcArr[e0], s1 = srcArr[e1];
        int s2 = srcArr[e2], s3 = srcArr[e3];
        float r0 = score[e0 * 8 + hh];
        float r1 = score[e1 * 8 + hh];
        float r2 = score[e2 * 8 + hh];
        float r3 = score[e3 * 8 + hh];
        unsigned u0 = Vb2[(size_t)s0 * 64 + lane];
        unsigned u1 = Vb2[(size_t)s1 * 64 + lane];
        unsigned u2 = Vb2[(size_t)s2 * 64 + lane];
        unsigned u3 = Vb2[(size_t)s3 * 64 + lane];
        float sc0 = __expf(fminf(fmaxf(r0, -5.f), 5.f));
        float sc1 = __expf(fminf(fmaxf(r1, -5.f), 5.f));
        float sc2 = __expf(fminf(fmaxf(r2, -5.f), 5.f));
        float sc3 = __expf(fminf(fmaxf(r3, -5.f), 5.f));
        union { float f; unsigned u; } c;
        c.u = u0 << 16;          accx += c.f * sc0;
        c.u = u0 & 0xFFFF0000u;  accy += c.f * sc0;
        c.u = u1 << 16;          accx += c.f * sc1;
        c.u = u1 & 0xFFFF0000u;  accy += c.f * sc1;
        c.u = u2 << 16;          accx += c.f * sc2;
        c.u = u2 & 0xFFFF0000u;  accy += c.f * sc2;
        c.u = u3 << 16;          accx += c.f * sc3;
        c.u = u3 & 0xFFFF0000u;  accy += c.f * sc3;
        zacc += (sc0 + sc1) + (sc2 + sc3);
    }
    for (; p < end; ++p) {
        int e = eid[p];
        int s = srcArr[e];
        float r = score[e * 8 + hh];
        float sc = __expf(fminf(fmaxf(r, -5.f), 5.f));
        unsigned u = Vb2[(size_t)s * 64 + lane];
        union { float f; unsigned u; } c;
        c.u = u << 16;          accx += c.f * sc;
        c.u = u & 0xFFFF0000u;  accy += c.f * sc;
        zacc += sc;
    }
    float rz = 1.f / (zacc + 1e-6f);
    unsigned lo = (unsigned short)f2bf(accx * rz);
    unsigned hi = (unsigned short)f2bf(accy * rz);
    wVn[(size_t)wid * 64 + lane] = lo | (hi << 16);
}

extern "C" void kernel_launch(void* const* d_in, const int* in_sizes, int n_in,
                              void* d_out, int out_size, void* d_ws, size_t ws_size,
                              hipStream_t stream)
{
    const float* h    = (const float*)d_in[0];
    const float* e    = (const float*)d_in[1];
    const float* adj2 = (const float*)d_in[2];
    const float* rel  = (const float*)d_in[3];
    const int*   src  = (const int*)d_in[4];
    const int*   dst  = (const int*)d_in[5];
    const int*   emap = (const int*)d_in[6];
    const float* Wq = (const float*)d_in[7];   const float* bq = (const float*)d_in[8];
    const float* Wk = (const float*)d_in[9];   const float* bk = (const float*)d_in[10];
    const float* Wv = (const float*)d_in[11];  const float* bv = (const float*)d_in[12];
    const float* Wpe = (const float*)d_in[13]; const float* bpe = (const float*)d_in[14];
    const float* Wap = (const float*)d_in[15]; const float* bap = (const float*)d_in[16];
    const float* Wout = (const float*)d_in[17]; const float* bout = (const float*)d_in[18];
    const float* Woute = (const float*)d_in[19]; const float* boute = (const float*)d_in[20];

    float* ws = (float*)d_ws;
    float*  score = ws;                         // 5,120,000 f32
    float*  pe    = ws + 5120000;               // 1,280,000 f32
    unsigned* wVn = (unsigned*)(ws + 6400000);  // 1,280,000 u32
    short*  Qb    = (short*)(ws + 7680000);     // 2,560,000 bf16
    short*  Kb    = (short*)(ws + 8960000);
    short*  Vb    = (short*)(ws + 10240000);
    short*  gsb   = (short*)(ws + 11520000);    // 1,280,000 bf16
    short*  WqT    = (short*)(ws + 12160000);   // 16384 bf16 each
    short*  WkT    = (short*)(ws + 12168192);
    short*  WvT    = (short*)(ws + 12176384);
    short*  WoutT  = (short*)(ws + 12184576);
    short*  WouteT = (short*)(ws + 12192768);
    short*  WpeT16 = (short*)(ws + 12200960);   // 2048 bf16
    short*  WcombP = (short*)(ws + 12201984);   // 4096 bf16
    float*  bcomb  = ws + 12204032;             // 128 f32
    float* h_out = (float*)d_out;
    float* e_out = (float*)d_out + 2560000;

    // CSR arrays alias Qb region (dead after score_kernel)
    int* hist   = (int*)Qb;
    int* offs   = (int*)Qb + 20000;
    int* cursor = (int*)Qb + 40001;
    int* eid    = (int*)Qb + 60001;

    wconv_kernel<<<dim3(16, 5), 256, 0, stream>>>(
        Wq, Wk, Wv, Wout, Woute, WqT, WkT, WvT, WoutT, WouteT);
    wpe_kernel<<<8, 256, 0, stream>>>(Wpe, WpeT16);
    wcomb_kernel<<<1, 128, 0, stream>>>(Wap, bap, Woute, boute, WcombP, bcomb);

    mfma_gemm_obf16<<<157, 256, 0, stream>>>(h, WqT, bq, Qb, NN);
    mfma_gemm_obf16<<<157, 256, 0, stream>>>(h, WkT, bk, Kb, NN);
    mfma_gemm_obf16<<<157, 256, 0, stream>>>(h, WvT, bv, Vb, NN);

    score_kernel<<<20000, 256, 0, stream>>>(Qb, Kb, src, dst, adj2, rel, score);

    mfma_pe<<<1250, 256, 0, stream>>>(e, WpeT16, bpe, pe);
    update_kernel<<<5000, 256, 0, stream>>>(emap, pe, score, gsb);
    mfma_eout<<<1250, 256, 0, stream>>>(e, WouteT, WcombP, bcomb, gsb, e_out);

    hipMemsetAsync(hist, 0, 20000 * sizeof(int), stream);
    hist_kernel<<<2500, 256, 0, stream>>>(dst, hist);
    scan_kernel<<<1, 256, 0, stream>>>(hist, offs, cursor);
    scatter_kernel<<<2500, 256, 0, stream>>>(dst, cursor, eid);
    csr_aggregate<<<5000, 256, 0, stream>>>((const unsigned*)Vb, src, score, offs, eid, wVn);

    mfma_gemm_abf16<<<157, 256, 0, stream>>>((const short*)wVn, WoutT, bout, h_out, NN);
}

// Round 7
// 308.838 us; speedup vs baseline: 2.2852x; 1.1751x over previous
//
#include <hip/hip_runtime.h>
#include <hip/hip_bf16.h>

#define NN 20000
#define EF 640000
#define EG 160000
#define SCAN_B 79   // ceil(NN/256)

typedef __attribute__((ext_vector_type(8))) short bf16x8;
typedef __attribute__((ext_vector_type(4))) float f32x4;

__device__ inline short f2bf(float f) {
    union { float f; unsigned u; } x; x.f = f;
    unsigned r = x.u + 0x7FFF + ((x.u >> 16) & 1);   // RNE
    return (short)(r >> 16);
}
__device__ inline float bf2f(short s) {
    union { float f; unsigned u; } x;
    x.u = ((unsigned)(unsigned short)s) << 16;
    return x.f;
}

// ---------------------------------------------------------------------------
// Weight transpose+convert: BT[n][k] = W[k][n] as bf16. 5 matrices via grid.y.
// ---------------------------------------------------------------------------
__global__ __launch_bounds__(256) void wconv_kernel(
    const float* __restrict__ W0, const float* __restrict__ W1,
    const float* __restrict__ W2, const float* __restrict__ W3,
    const float* __restrict__ W4, short* __restrict__ B0,
    short* __restrict__ B1, short* __restrict__ B2,
    short* __restrict__ B3, short* __restrict__ B4)
{
    const float* W; short* B;
    switch (blockIdx.y) {
        case 0: W = W0; B = B0; break;
        case 1: W = W1; B = B1; break;
        case 2: W = W2; B = B2; break;
        case 3: W = W3; B = B3; break;
        default: W = W4; B = B4; break;
    }
    int i = blockIdx.x * 256 + threadIdx.x;   // 0..4095
    int n = i >> 5;
    int k0 = (i & 31) * 4;
    #pragma unroll
    for (int j = 0; j < 4; ++j)
        B[n * 128 + k0 + j] = f2bf(W[(k0 + j) * 128 + n]);
}

// WpeT16[n][k]: n<8 -> Wpe[k][n], else 0 (pad to N=16)
__global__ __launch_bounds__(256) void wpe_kernel(
    const float* __restrict__ Wpe, short* __restrict__ WpeT16)
{
    int i = blockIdx.x * 256 + threadIdx.x;   // 0..2047
    int n = i >> 7, k = i & 127;
    WpeT16[n * 128 + k] = (n < 8) ? f2bf(Wpe[k * 8 + n]) : 0;
}

// Wcomb = Wap@Woute -> WcombP[j][kk] (kk<8; pad to 32), bcomb = bap@Woute+boute
__global__ __launch_bounds__(128) void wcomb_kernel(
    const float* __restrict__ Wap, const float* __restrict__ bap,
    const float* __restrict__ Woute, const float* __restrict__ boute,
    short* __restrict__ WcombP, float* __restrict__ bcomb)
{
    int j = threadIdx.x;   // 0..127
    float bc = boute[j];
    for (int k = 0; k < 128; ++k) bc += bap[k] * Woute[k * 128 + j];
    bcomb[j] = bc;
    #pragma unroll
    for (int i = 0; i < 8; ++i) {
        float s = 0.f;
        for (int k = 0; k < 128; ++k) s += Wap[i * 128 + k] * Woute[k * 128 + j];
        WcombP[j * 32 + i] = f2bf(s);
    }
    #pragma unroll
    for (int i = 8; i < 32; ++i) WcombP[j * 32 + i] = 0;
}

// ---------------------------------------------------------------------------
// MFMA GEMM N=128,K=128, f32 A (cvt in-reg), bf16 OUT (for Q/K/V).
// ---------------------------------------------------------------------------
__global__ __launch_bounds__(256) void mfma_gemm_obf16(
    const float* __restrict__ Ap, const short* __restrict__ BT,
    const float* __restrict__ bias, short* __restrict__ out, int M)
{
    int lane = threadIdx.x & 63;
    int w = threadIdx.x >> 6;
    int row0 = blockIdx.x * 128 + w * 32;
    int l15 = lane & 15, lhi = lane >> 4;

    bf16x8 a[2][4];
    #pragma unroll
    for (int m = 0; m < 2; ++m) {
        int r = row0 + m * 16 + l15;
        bool ok = r < M;
        #pragma unroll
        for (int ks = 0; ks < 4; ++ks) {
            if (ok) {
                const float* ap = Ap + (size_t)r * 128 + ks * 32 + lhi * 8;
                float4 f0 = *(const float4*)ap;
                float4 f1 = *(const float4*)(ap + 4);
                a[m][ks][0] = f2bf(f0.x); a[m][ks][1] = f2bf(f0.y);
                a[m][ks][2] = f2bf(f0.z); a[m][ks][3] = f2bf(f0.w);
                a[m][ks][4] = f2bf(f1.x); a[m][ks][5] = f2bf(f1.y);
                a[m][ks][6] = f2bf(f1.z); a[m][ks][7] = f2bf(f1.w);
            } else {
                #pragma unroll
                for (int j = 0; j < 8; ++j) a[m][ks][j] = 0;
            }
        }
    }
    f32x4 acc[2][8];
    #pragma unroll
    for (int m = 0; m < 2; ++m)
        #pragma unroll
        for (int n = 0; n < 8; ++n)
            acc[m][n] = (f32x4){0.f, 0.f, 0.f, 0.f};

    #pragma unroll
    for (int n = 0; n < 8; ++n)
        #pragma unroll
        for (int ks = 0; ks < 4; ++ks) {
            bf16x8 b = *(const bf16x8*)(BT + (size_t)(n * 16 + l15) * 128 + ks * 32 + lhi * 8);
            acc[0][n] = __builtin_amdgcn_mfma_f32_16x16x32_bf16(a[0][ks], b, acc[0][n], 0, 0, 0);
            acc[1][n] = __builtin_amdgcn_mfma_f32_16x16x32_bf16(a[1][ks], b, acc[1][n], 0, 0, 0);
        }

    #pragma unroll
    for (int m = 0; m < 2; ++m)
        #pragma unroll
        for (int n = 0; n < 8; ++n) {
            int col = n * 16 + l15;
            float bs = bias[col];
            #pragma unroll
            for (int r4 = 0; r4 < 4; ++r4) {
                int row = row0 + m * 16 + lhi * 4 + r4;
                if (row < M) out[(size_t)row * 128 + col] = f2bf(acc[m][n][r4] + bs);
            }
        }
}

// ---------------------------------------------------------------------------
// MFMA GEMM N=128,K=128, bf16 A, f32 OUT (for h_out from wVn).
// ---------------------------------------------------------------------------
__global__ __launch_bounds__(256) void mfma_gemm_abf16(
    const short* __restrict__ Ap, const short* __restrict__ BT,
    const float* __restrict__ bias, float* __restrict__ out, int M)
{
    int lane = threadIdx.x & 63;
    int w = threadIdx.x >> 6;
    int row0 = blockIdx.x * 128 + w * 32;
    int l15 = lane & 15, lhi = lane >> 4;

    bf16x8 a[2][4];
    #pragma unroll
    for (int m = 0; m < 2; ++m) {
        int r = row0 + m * 16 + l15;
        bool ok = r < M;
        #pragma unroll
        for (int ks = 0; ks < 4; ++ks) {
            if (ok) a[m][ks] = *(const bf16x8*)(Ap + (size_t)r * 128 + ks * 32 + lhi * 8);
            else {
                #pragma unroll
                for (int j = 0; j < 8; ++j) a[m][ks][j] = 0;
            }
        }
    }
    f32x4 acc[2][8];
    #pragma unroll
    for (int m = 0; m < 2; ++m)
        #pragma unroll
        for (int n = 0; n < 8; ++n)
            acc[m][n] = (f32x4){0.f, 0.f, 0.f, 0.f};

    #pragma unroll
    for (int n = 0; n < 8; ++n)
        #pragma unroll
        for (int ks = 0; ks < 4; ++ks) {
            bf16x8 b = *(const bf16x8*)(BT + (size_t)(n * 16 + l15) * 128 + ks * 32 + lhi * 8);
            acc[0][n] = __builtin_amdgcn_mfma_f32_16x16x32_bf16(a[0][ks], b, acc[0][n], 0, 0, 0);
            acc[1][n] = __builtin_amdgcn_mfma_f32_16x16x32_bf16(a[1][ks], b, acc[1][n], 0, 0, 0);
        }

    #pragma unroll
    for (int m = 0; m < 2; ++m)
        #pragma unroll
        for (int n = 0; n < 8; ++n) {
            int col = n * 16 + l15;
            float bs = bias[col];
            #pragma unroll
            for (int r4 = 0; r4 < 4; ++r4) {
                int row = row0 + m * 16 + lhi * 4 + r4;
                if (row < M) out[(size_t)row * 128 + col] = acc[m][n][r4] + bs;
            }
        }
}

// ---------------------------------------------------------------------------
// pe = e @ Wpe + bpe  (MFMA, N=16 padded, only cols 0..7 written)
// ---------------------------------------------------------------------------
__global__ __launch_bounds__(256) void mfma_pe(
    const float* __restrict__ Ap, const short* __restrict__ WpeT16,
    const float* __restrict__ bpe, float* __restrict__ pe)
{
    int lane = threadIdx.x & 63;
    int w = threadIdx.x >> 6;
    int row0 = blockIdx.x * 128 + w * 32;
    int l15 = lane & 15, lhi = lane >> 4;

    bf16x8 a[2][4];
    #pragma unroll
    for (int m = 0; m < 2; ++m) {
        int r = row0 + m * 16 + l15;
        #pragma unroll
        for (int ks = 0; ks < 4; ++ks) {
            const float* ap = Ap + (size_t)r * 128 + ks * 32 + lhi * 8;
            float4 f0 = *(const float4*)ap;
            float4 f1 = *(const float4*)(ap + 4);
            a[m][ks][0] = f2bf(f0.x); a[m][ks][1] = f2bf(f0.y);
            a[m][ks][2] = f2bf(f0.z); a[m][ks][3] = f2bf(f0.w);
            a[m][ks][4] = f2bf(f1.x); a[m][ks][5] = f2bf(f1.y);
            a[m][ks][6] = f2bf(f1.z); a[m][ks][7] = f2bf(f1.w);
        }
    }
    f32x4 acc[2];
    acc[0] = (f32x4){0.f, 0.f, 0.f, 0.f};
    acc[1] = (f32x4){0.f, 0.f, 0.f, 0.f};
    #pragma unroll
    for (int ks = 0; ks < 4; ++ks) {
        bf16x8 b = *(const bf16x8*)(WpeT16 + (size_t)l15 * 128 + ks * 32 + lhi * 8);
        acc[0] = __builtin_amdgcn_mfma_f32_16x16x32_bf16(a[0][ks], b, acc[0], 0, 0, 0);
        acc[1] = __builtin_amdgcn_mfma_f32_16x16x32_bf16(a[1][ks], b, acc[1], 0, 0, 0);
    }
    if (l15 < 8) {
        float bs = bpe[l15];
        #pragma unroll
        for (int m = 0; m < 2; ++m)
            #pragma unroll
            for (int r4 = 0; r4 < 4; ++r4) {
                int row = row0 + m * 16 + lhi * 4 + r4;
                pe[(size_t)row * 8 + l15] = acc[m][r4] + bs;
            }
    }
}

// ---------------------------------------------------------------------------
// update: gsb = bf16(score1[emap]); score[emap] = clip(score1) + pe
// ---------------------------------------------------------------------------
__global__ __launch_bounds__(256) void update_kernel(
    const int* __restrict__ emap, const float* __restrict__ pe,
    float* __restrict__ score, short* __restrict__ gsb)
{
    int idx = blockIdx.x * 256 + threadIdx.x;   // over EG*8
    if (idx >= EG * 8) return;
    int i = idx >> 3, hh = idx & 7;
    int fidx = emap[i];
    float gs = score[fidx * 8 + hh];
    gsb[idx] = f2bf(gs);
    score[fidx * 8 + hh] = fminf(fmaxf(gs, -5.f), 5.f) + pe[idx];
}

// ---------------------------------------------------------------------------
// e_out = e @ Woute + gs @ Wcomb + bcomb   (fused, MFMA, f32 out)
// ---------------------------------------------------------------------------
__global__ __launch_bounds__(256) void mfma_eout(
    const float* __restrict__ Ap, const short* __restrict__ WouteT,
    const short* __restrict__ WcombP, const float* __restrict__ bcomb,
    const short* __restrict__ gsb, float* __restrict__ out)
{
    int lane = threadIdx.x & 63;
    int w = threadIdx.x >> 6;
    int row0 = blockIdx.x * 128 + w * 32;
    int l15 = lane & 15, lhi = lane >> 4;

    bf16x8 a[2][4], ag[2];
    #pragma unroll
    for (int m = 0; m < 2; ++m) {
        int r = row0 + m * 16 + l15;
        #pragma unroll
        for (int ks = 0; ks < 4; ++ks) {
            const float* ap = Ap + (size_t)r * 128 + ks * 32 + lhi * 8;
            float4 f0 = *(const float4*)ap;
            float4 f1 = *(const float4*)(ap + 4);
            a[m][ks][0] = f2bf(f0.x); a[m][ks][1] = f2bf(f0.y);
            a[m][ks][2] = f2bf(f0.z); a[m][ks][3] = f2bf(f0.w);
            a[m][ks][4] = f2bf(f1.x); a[m][ks][5] = f2bf(f1.y);
            a[m][ks][6] = f2bf(f1.z); a[m][ks][7] = f2bf(f1.w);
        }
        if (lhi == 0) ag[m] = *(const bf16x8*)(gsb + (size_t)r * 8);
        else {
            #pragma unroll
            for (int j = 0; j < 8; ++j) ag[m][j] = 0;
        }
    }
    f32x4 acc[2][8];
    #pragma unroll
    for (int m = 0; m < 2; ++m)
        #pragma unroll
        for (int n = 0; n < 8; ++n)
            acc[m][n] = (f32x4){0.f, 0.f, 0.f, 0.f};

    #pragma unroll
    for (int n = 0; n < 8; ++n) {
        #pragma unroll
        for (int ks = 0; ks < 4; ++ks) {
            bf16x8 b = *(const bf16x8*)(WouteT + (size_t)(n * 16 + l15) * 128 + ks * 32 + lhi * 8);
            acc[0][n] = __builtin_amdgcn_mfma_f32_16x16x32_bf16(a[0][ks], b, acc[0][n], 0, 0, 0);
            acc[1][n] = __builtin_amdgcn_mfma_f32_16x16x32_bf16(a[1][ks], b, acc[1][n], 0, 0, 0);
        }
        bf16x8 bg = *(const bf16x8*)(WcombP + (size_t)(n * 16 + l15) * 32 + lhi * 8);
        acc[0][n] = __builtin_amdgcn_mfma_f32_16x16x32_bf16(ag[0], bg, acc[0][n], 0, 0, 0);
        acc[1][n] = __builtin_amdgcn_mfma_f32_16x16x32_bf16(ag[1], bg, acc[1][n], 0, 0, 0);
    }

    #pragma unroll
    for (int m = 0; m < 2; ++m)
        #pragma unroll
        for (int n = 0; n < 8; ++n) {
            int col = n * 16 + l15;
            float bs = bcomb[col];
            #pragma unroll
            for (int r4 = 0; r4 < 4; ++r4) {
                int row = row0 + m * 16 + lhi * 4 + r4;
                out[(size_t)row * 128 + col] = acc[m][n][r4] + bs;
            }
        }
}

// ---------------------------------------------------------------------------
// score1 for all full-graph edges: 8 lanes per edge, bf16 Q/K gathers
// ---------------------------------------------------------------------------
__global__ __launch_bounds__(256) void score_kernel(
    const short* __restrict__ Qb, const short* __restrict__ Kb,
    const int* __restrict__ src, const int* __restrict__ dst,
    const float* __restrict__ adj2, const float* __restrict__ rel,
    float* __restrict__ score)
{
    int tid = blockIdx.x * 256 + threadIdx.x;   // over EF*8
    if (tid >= EF * 8) return;
    int e = tid >> 3, hh = tid & 7;
    int s = src[e], d = dst[e];
    const bf16x8* Kp = (const bf16x8*)(Kb + (size_t)s * 128 + hh * 16);
    const bf16x8* Qp = (const bf16x8*)(Qb + (size_t)d * 128 + hh * 16);
    bf16x8 k0 = Kp[0], k1 = Kp[1];
    bf16x8 q0 = Qp[0], q1 = Qp[1];
    float dot = 0.f;
    #pragma unroll
    for (int j = 0; j < 8; ++j) dot += bf2f(k0[j]) * bf2f(q0[j]);
    #pragma unroll
    for (int j = 0; j < 8; ++j) dot += bf2f(k1[j]) * bf2f(q1[j]);
    dot *= 0.25f;
    float sc = __expf(fminf(fmaxf(dot, -5.f), 5.f) * adj2[e]) + rel[e];
    score[tid] = sc;
}

// ---------------------------------------------------------------------------
// CSR build: histogram + 3-stage hierarchical scan + scatter
// ---------------------------------------------------------------------------
__global__ __launch_bounds__(256) void hist_kernel(
    const int* __restrict__ dst, int* __restrict__ hist)
{
    int i = blockIdx.x * 256 + threadIdx.x;
    if (i < EF) atomicAdd(&hist[dst[i]], 1);
}

// stage 1: per-block inclusive scan + block totals
__global__ __launch_bounds__(256) void scan_part(
    const int* __restrict__ hist, int* __restrict__ pref,
    int* __restrict__ bsum)
{
    __shared__ int tmp[256];
    int tid = threadIdx.x;
    int idx = blockIdx.x * 256 + tid;
    int v = (idx < NN) ? hist[idx] : 0;
    tmp[tid] = v;
    __syncthreads();
    for (int s = 1; s < 256; s <<= 1) {
        int t = (tid >= s) ? tmp[tid - s] : 0;
        __syncthreads();
        tmp[tid] += t;
        __syncthreads();
    }
    if (idx < NN) pref[idx] = tmp[tid];          // inclusive within block
    if (tid == 255) bsum[blockIdx.x] = tmp[255];
}

// stage 2: exclusive scan of SCAN_B block totals (1 block)
__global__ __launch_bounds__(128) void scan_bsum(
    const int* __restrict__ bsum, int* __restrict__ bpref)
{
    __shared__ int tmp[128];
    int tid = threadIdx.x;
    int v = (tid < SCAN_B) ? bsum[tid] : 0;
    tmp[tid] = v;
    __syncthreads();
    for (int s = 1; s < 128; s <<= 1) {
        int t = (tid >= s) ? tmp[tid - s] : 0;
        __syncthreads();
        tmp[tid] += t;
        __syncthreads();
    }
    bpref[tid] = tmp[tid] - v;                   // exclusive
}

// stage 3: combine -> exclusive offs + cursor
__global__ __launch_bounds__(256) void scan_add(
    const int* __restrict__ pref, const int* __restrict__ bpref,
    const int* __restrict__ hist, int* __restrict__ offs,
    int* __restrict__ cursor)
{
    int idx = blockIdx.x * 256 + threadIdx.x;
    if (idx < NN) {
        int excl = pref[idx] - hist[idx] + bpref[idx >> 8];
        offs[idx] = excl;
        cursor[idx] = excl;
    }
    if (idx == 0) offs[NN] = EF;
}

__global__ __launch_bounds__(256) void scatter_kernel(
    const int* __restrict__ dst, int* __restrict__ cursor,
    int* __restrict__ eid)
{
    int i = blockIdx.x * 256 + threadIdx.x;
    if (i < EF) {
        int p = atomicAdd(&cursor[dst[i]], 1);
        eid[p] = i;
    }
}

// ---------------------------------------------------------------------------
// CSR aggregation: wave per node; exp folded in; bf16 V; normalized bf16 out.
// ---------------------------------------------------------------------------
__global__ __launch_bounds__(256) void csr_aggregate(
    const unsigned* __restrict__ Vb2, const int* __restrict__ srcArr,
    const float* __restrict__ score, const int* __restrict__ offs,
    const int* __restrict__ eid, unsigned* __restrict__ wVn)
{
    int lane = threadIdx.x & 63;
    int wid = (blockIdx.x << 2) | (threadIdx.x >> 6);
    if (wid >= NN) return;
    int beg = offs[wid], end = offs[wid + 1];
    int hh = lane >> 3;

    float accx = 0.f, accy = 0.f, zacc = 0.f;
    int p = beg;
    for (; p + 4 <= end; p += 4) {
        int e0 = eid[p],     e1 = eid[p + 1];
        int e2 = eid[p + 2], e3 = eid[p + 3];
        int s0 = srcArr[e0], s1 = srcArr[e1];
        int s2 = srcArr[e2], s3 = srcArr[e3];
        float r0 = score[e0 * 8 + hh];
        float r1 = score[e1 * 8 + hh];
        float r2 = score[e2 * 8 + hh];
        float r3 = score[e3 * 8 + hh];
        unsigned u0 = Vb2[(size_t)s0 * 64 + lane];
        unsigned u1 = Vb2[(size_t)s1 * 64 + lane];
        unsigned u2 = Vb2[(size_t)s2 * 64 + lane];
        unsigned u3 = Vb2[(size_t)s3 * 64 + lane];
        float sc0 = __expf(fminf(fmaxf(r0, -5.f), 5.f));
        float sc1 = __expf(fminf(fmaxf(r1, -5.f), 5.f));
        float sc2 = __expf(fminf(fmaxf(r2, -5.f), 5.f));
        float sc3 = __expf(fminf(fmaxf(r3, -5.f), 5.f));
        union { float f; unsigned u; } c;
        c.u = u0 << 16;          accx += c.f * sc0;
        c.u = u0 & 0xFFFF0000u;  accy += c.f * sc0;
        c.u = u1 << 16;          accx += c.f * sc1;
        c.u = u1 & 0xFFFF0000u;  accy += c.f * sc1;
        c.u = u2 << 16;          accx += c.f * sc2;
        c.u = u2 & 0xFFFF0000u;  accy += c.f * sc2;
        c.u = u3 << 16;          accx += c.f * sc3;
        c.u = u3 & 0xFFFF0000u;  accy += c.f * sc3;
        zacc += (sc0 + sc1) + (sc2 + sc3);
    }
    for (; p < end; ++p) {
        int e = eid[p];
        int s = srcArr[e];
        float r = score[e * 8 + hh];
        float sc = __expf(fminf(fmaxf(r, -5.f), 5.f));
        unsigned u = Vb2[(size_t)s * 64 + lane];
        union { float f; unsigned u; } c;
        c.u = u << 16;          accx += c.f * sc;
        c.u = u & 0xFFFF0000u;  accy += c.f * sc;
        zacc += sc;
    }
    float rz = 1.f / (zacc + 1e-6f);
    unsigned lo = (unsigned short)f2bf(accx * rz);
    unsigned hi = (unsigned short)f2bf(accy * rz);
    wVn[(size_t)wid * 64 + lane] = lo | (hi << 16);
}

extern "C" void kernel_launch(void* const* d_in, const int* in_sizes, int n_in,
                              void* d_out, int out_size, void* d_ws, size_t ws_size,
                              hipStream_t stream)
{
    const float* h    = (const float*)d_in[0];
    const float* e    = (const float*)d_in[1];
    const float* adj2 = (const float*)d_in[2];
    const float* rel  = (const float*)d_in[3];
    const int*   src  = (const int*)d_in[4];
    const int*   dst  = (const int*)d_in[5];
    const int*   emap = (const int*)d_in[6];
    const float* Wq = (const float*)d_in[7];   const float* bq = (const float*)d_in[8];
    const float* Wk = (const float*)d_in[9];   const float* bk = (const float*)d_in[10];
    const float* Wv = (const float*)d_in[11];  const float* bv = (const float*)d_in[12];
    const float* Wpe = (const float*)d_in[13]; const float* bpe = (const float*)d_in[14];
    const float* Wap = (const float*)d_in[15]; const float* bap = (const float*)d_in[16];
    const float* Wout = (const float*)d_in[17]; const float* bout = (const float*)d_in[18];
    const float* Woute = (const float*)d_in[19]; const float* boute = (const float*)d_in[20];

    float* ws = (float*)d_ws;
    float*  score = ws;                         // 5,120,000 f32
    float*  pe    = ws + 5120000;               // 1,280,000 f32
    unsigned* wVn = (unsigned*)(ws + 6400000);  // 1,280,000 u32
    short*  Qb    = (short*)(ws + 7680000);     // 2,560,000 bf16
    short*  Kb    = (short*)(ws + 8960000);
    short*  Vb    = (short*)(ws + 10240000);
    short*  gsb   = (short*)(ws + 11520000);    // 1,280,000 bf16
    short*  WqT    = (short*)(ws + 12160000);   // 16384 bf16 each
    short*  WkT    = (short*)(ws + 12168192);
    short*  WvT    = (short*)(ws + 12176384);
    short*  WoutT  = (short*)(ws + 12184576);
    short*  WouteT = (short*)(ws + 12192768);
    short*  WpeT16 = (short*)(ws + 12200960);   // 2048 bf16
    short*  WcombP = (short*)(ws + 12201984);   // 4096 bf16
    float*  bcomb  = ws + 12204032;             // 128 f32
    float* h_out = (float*)d_out;
    float* e_out = (float*)d_out + 2560000;

    // CSR arrays alias Qb region (dead after score_kernel)
    int* hist   = (int*)Qb;                    // 20,000
    int* offs   = (int*)Qb + 20000;            // 20,001
    int* cursor = (int*)Qb + 40001;            // 20,000
    int* eid    = (int*)Qb + 60001;            // 640,000
    int* pref   = (int*)Qb + 700001;           // 20,000
    int* bsum   = (int*)Qb + 720001;           // 128
    int* bpref  = (int*)Qb + 720129;           // 128

    wconv_kernel<<<dim3(16, 5), 256, 0, stream>>>(
        Wq, Wk, Wv, Wout, Woute, WqT, WkT, WvT, WoutT, WouteT);
    wpe_kernel<<<8, 256, 0, stream>>>(Wpe, WpeT16);
    wcomb_kernel<<<1, 128, 0, stream>>>(Wap, bap, Woute, boute, WcombP, bcomb);

    mfma_gemm_obf16<<<157, 256, 0, stream>>>(h, WqT, bq, Qb, NN);
    mfma_gemm_obf16<<<157, 256, 0, stream>>>(h, WkT, bk, Kb, NN);
    mfma_gemm_obf16<<<157, 256, 0, stream>>>(h, WvT, bv, Vb, NN);

    score_kernel<<<20000, 256, 0, stream>>>(Qb, Kb, src, dst, adj2, rel, score);

    mfma_pe<<<1250, 256, 0, stream>>>(e, WpeT16, bpe, pe);
    update_kernel<<<5000, 256, 0, stream>>>(emap, pe, score, gsb);
    mfma_eout<<<1250, 256, 0, stream>>>(e, WouteT, WcombP, bcomb, gsb, e_out);

    hipMemsetAsync(hist, 0, 20000 * sizeof(int), stream);
    hist_kernel<<<2500, 256, 0, stream>>>(dst, hist);
    scan_part<<<SCAN_B, 256, 0, stream>>>(hist, pref, bsum);
    scan_bsum<<<1, 128, 0, stream>>>(bsum, bpref);
    scan_add<<<SCAN_B, 256, 0, stream>>>(pref, bpref, hist, offs, cursor);
    scatter_kernel<<<2500, 256, 0, stream>>>(dst, cursor, eid);
    csr_aggregate<<<5000, 256, 0, stream>>>((const unsigned*)Vb, src, score, offs, eid, wVn);

    mfma_gemm_abf16<<<157, 256, 0, stream>>>((const short*)wVn, WoutT, bout, h_out, NN);
}